// Round 1
// baseline (4113.980 us; speedup 1.0000x reference)
//
#include <hip/hip_runtime.h>
#include <hip/hip_bf16.h>
#include <math.h>

// Problem constants
#define NNODES 10000
#define NEDGE  160000
// MULT=16, NL=2, DIM=4, EDGE_DIM=32, HID=128, RANK=8, H=4, HM=4

typedef unsigned short u16;
using bf16x8 = __attribute__((ext_vector_type(8))) short;
using f32x4  = __attribute__((ext_vector_type(4))) float;

static __device__ __forceinline__ u16 f2bf(float x) {
  unsigned u = __float_as_uint(x);
  u += 0x7FFFu + ((u >> 16) & 1u);     // RNE
  return (u16)(u >> 16);
}
static __device__ __forceinline__ float bf2f(u16 h) {
  return __uint_as_float(((unsigned)h) << 16);
}

// ---------------- zero init (harness poisons d_out/d_ws with 0xAA) ----------
__global__ void zero_kernel(float* __restrict__ outp, float* __restrict__ den) {
  int i = blockIdx.x * 256 + threadIdx.x;
  if (i < NNODES * 64) outp[i] = 0.0f;
  if (i < NNODES * 4)  den[i]  = 0.0f;
}

// ---------------- weight swizzle: (128,256) fp32 -> B-frag-major bf16 -------
// Wsw element at ((ntg*4+ks)*64 + lane)*8 + j  ==  W[k][col],
//   k = ks*32 + (lane>>4)*8 + j, col = ntg*16 + (lane&15)
// so a wave's 64 lanes read one contiguous 1 KiB line per B fragment.
__global__ void prep_w_kernel(const float* __restrict__ kwr, const float* __restrict__ kwl,
                              const float* __restrict__ vwr, const float* __restrict__ vwl,
                              u16* __restrict__ Wsw) {
  int idx = blockIdx.x * 256 + threadIdx.x;      // 0..131071  (4 slots x 32768)
  int slot = idx >> 15;
  int w = idx & 32767;
  int j = w & 7, lane = (w >> 3) & 63, ks = (w >> 9) & 3, ntg = w >> 11;
  int k   = ks * 32 + ((lane >> 4) << 3) + j;
  int col = (ntg << 4) + (lane & 15);
  const float* s = (slot == 0) ? kwr : (slot == 1) ? kwl : (slot == 2) ? vwr : vwl;
  Wsw[idx] = f2bf(s[k * 256 + col]);
}

// ---------------- Q: equivariant linear (fp32, tiny) ------------------------
// q[n][o][d] = sum_m q_w[(IDX[d]*16+o)*16+m] * f[n][m][d];  q[:, :, 0] += q_b
__global__ void q_kernel(const float* __restrict__ f, const float* __restrict__ qw,
                         const float* __restrict__ qb, float* __restrict__ q) {
  int i = blockIdx.x * 256 + threadIdx.x;        // n*16 + o
  if (i >= NNODES * 16) return;
  int n = i >> 4, o = i & 15;
  const float* frow = f + (size_t)n * 64;
  float o0 = 0.f, o1 = 0.f, o2 = 0.f, o3 = 0.f;
#pragma unroll
  for (int m = 0; m < 16; ++m) {
    float w0 = qw[o * 16 + m];          // irrep block 0 (d = 0)
    float w1 = qw[(16 + o) * 16 + m];   // irrep block 1 (d = 1..3)
    o0 += w0 * frow[m * 4 + 0];
    o1 += w1 * frow[m * 4 + 1];
    o2 += w1 * frow[m * 4 + 2];
    o3 += w1 * frow[m * 4 + 3];
  }
  o0 += qb[o];
  float4 r = make_float4(o0, o1, o2, o3);
  *(float4*)(q + (size_t)i * 4) = r;
}

// ---------------- t: basis contraction (shared by both convs) ---------------
// t[e][m*2+l] = sum_d f[src[e]][m][d] * b1[e][d][l]   -> bf16
__global__ void t_kernel(const float* __restrict__ f, const float* __restrict__ b1,
                         const int* __restrict__ src, u16* __restrict__ tbuf) {
  int e = blockIdx.x * 256 + threadIdx.x;        // grid covers exactly NEDGE
  const float* frow = f + (size_t)src[e] * 64;
  const float* be = b1 + (size_t)e * 8;          // (4,2)
  float b[8];
#pragma unroll
  for (int i = 0; i < 8; ++i) b[i] = be[i];
  u16* tp = tbuf + (size_t)e * 32;
#pragma unroll
  for (int m = 0; m < 16; ++m) {
    float f0 = frow[m * 4 + 0], f1 = frow[m * 4 + 1], f2 = frow[m * 4 + 2], f3 = frow[m * 4 + 3];
#pragma unroll
    for (int l = 0; l < 2; ++l) {
      float t = f0 * b[0 * 2 + l] + f1 * b[1 * 2 + l] + f2 * b[2 * 2 + l] + f3 * b[3 * 2 + l];
      tp[m * 2 + l] = f2bf(t);
    }
  }
}

// ---------------- radial hidden layer: H = gelu(EF @ w1 + b1) -> bf16 -------
__global__ void h_kernel(const float* __restrict__ ef, const float* __restrict__ w1,
                         const float* __restrict__ b1h, u16* __restrict__ H) {
  __shared__ float sW[32 * 128];
  __shared__ float sE[32 * 32];
  int tid = threadIdx.x;
  int e0 = blockIdx.x * 32;
  for (int i = tid; i < 1024; i += 256)
    *(float4*)&sW[i * 4] = *(const float4*)&w1[i * 4];
  *(float4*)&sE[tid * 4] = *(const float4*)&ef[(size_t)e0 * 32 + tid * 4];
  __syncthreads();
  int el = tid >> 3;              // 0..31 local edge
  int j0 = (tid & 7) << 4;        // 16 hidden units per thread
  float acc[16];
#pragma unroll
  for (int jj = 0; jj < 16; ++jj) acc[jj] = 0.f;
  for (int i = 0; i < 32; ++i) {
    float ev = sE[el * 32 + i];
    const float* wrow = &sW[i * 128 + j0];
#pragma unroll
    for (int jj = 0; jj < 16; ++jj) acc[jj] += ev * wrow[jj];
  }
  size_t base = (size_t)(e0 + el) * 128 + j0;
#pragma unroll
  for (int jj = 0; jj < 16; ++jj) {
    float x = acc[jj] + b1h[j0 + jj];
    float g = 0.5f * x * (1.0f + erff(x * 0.7071067811865475f)); // exact gelu
    H[base + jj] = f2bf(g);
  }
}

// ---------------- MFMA GEMM core macro: 64 edges x 256 cols x K=128 ---------
// A tile in LDS (row-major, pitch 136 bf16 -> 2-way bank aliasing = free).
// B fragments straight from L2 (pre-swizzled contiguous per wave).
#define GEMM_CORE()                                                                  \
  int tid = threadIdx.x;                                                             \
  int wave = tid >> 6, lane = tid & 63, quad = lane >> 4, l16 = lane & 15;           \
  size_t e0 = (size_t)blockIdx.x * 64;                                               \
  for (int c = tid; c < 1024; c += 256) {                                            \
    int row = c >> 4, off = (c & 15) << 3;                                           \
    *(uint4*)&sA[row * 136 + off] = *(const uint4*)&H[(e0 + row) * 128 + off];       \
  }                                                                                  \
  __syncthreads();                                                                   \
  f32x4 acc[4][4];                                                                   \
  _Pragma("unroll") for (int mt = 0; mt < 4; ++mt)                                   \
    _Pragma("unroll") for (int nt = 0; nt < 4; ++nt)                                 \
      acc[mt][nt] = (f32x4){0.f, 0.f, 0.f, 0.f};                                     \
  _Pragma("unroll") for (int ks = 0; ks < 4; ++ks) {                                 \
    bf16x8 a[4], b[4];                                                               \
    _Pragma("unroll") for (int mt = 0; mt < 4; ++mt)                                 \
      a[mt] = *(const bf16x8*)&sA[(mt * 16 + l16) * 136 + ks * 32 + quad * 8];       \
    _Pragma("unroll") for (int nt = 0; nt < 4; ++nt)                                 \
      b[nt] = *(const bf16x8*)&Wsw[(size_t)(((wave * 4 + nt) * 4 + ks) * 64 + lane) * 8]; \
    _Pragma("unroll") for (int mt = 0; mt < 4; ++mt)                                 \
      _Pragma("unroll") for (int nt = 0; nt < 4; ++nt)                               \
        acc[mt][nt] = __builtin_amdgcn_mfma_f32_16x16x32_bf16(a[mt], b[nt],          \
                                                              acc[mt][nt], 0, 0, 0); \
  }

#define DUMP_MT(mt)                                                                  \
  _Pragma("unroll") for (int nt = 0; nt < 4; ++nt) {                                 \
    int colg = (wave * 4 + nt) * 16 + l16;                                           \
    _Pragma("unroll") for (int r = 0; r < 4; ++r)                                    \
      sD[(quad * 4 + r) * 260 + colg] = acc[mt][nt][r];                              \
  }

// GEMM-R: right = H @ wr + br ; epilogue u[e][p] = sum_c right[e][p*32+c]*t[e][c]
__global__ void __launch_bounds__(256) gemm_right_kernel(
    const u16* __restrict__ H, const u16* __restrict__ Wsw,
    const float* __restrict__ bias, const u16* __restrict__ tbuf,
    float* __restrict__ ubuf) {
  __shared__ alignas(16) u16 sA[64 * 136];
  __shared__ float sD[16 * 260];
  GEMM_CORE()
#pragma unroll
  for (int mt = 0; mt < 4; ++mt) {
    DUMP_MT(mt)
    __syncthreads();
    if (tid < 128) {
      int el = tid >> 3, p = tid & 7;
      size_t e = e0 + mt * 16 + el;
      const u16* te = tbuf + e * 32;
      const float* bp = bias + p * 32;
      const float* dp = &sD[el * 260 + p * 32];
      float s = 0.f;
#pragma unroll
      for (int c = 0; c < 32; ++c) s += (dp[c] + bp[c]) * bf2f(te[c]);
      ubuf[e * 8 + p] = s;
    }
    __syncthreads();
  }
}

// GEMM-L: left = H @ wl + bl ; epilogue t2[r]=sum_p left[r*8+p]*u[p];
// out[e][m][d] = t2[m*2+0]*b2[e][0][d] + t2[m*2+1]*b2[e][1][d]  -> bf16
__global__ void __launch_bounds__(256) gemm_left_kernel(
    const u16* __restrict__ H, const u16* __restrict__ Wsw,
    const float* __restrict__ bias, const float* __restrict__ ubuf,
    const float* __restrict__ b2, u16* __restrict__ kv) {
  __shared__ alignas(16) u16 sA[64 * 136];
  __shared__ float sD[16 * 260];
  GEMM_CORE()
#pragma unroll
  for (int mt = 0; mt < 4; ++mt) {
    DUMP_MT(mt)
    __syncthreads();
    {
      int el = tid >> 4, m = tid & 15;
      size_t e = e0 + mt * 16 + el;
      const float* ue = ubuf + e * 8;
      const float* b2e = b2 + e * 8;   // (2,4)
      float t2l[2];
#pragma unroll
      for (int l = 0; l < 2; ++l) {
        int r = m * 2 + l;
        const float* dp = &sD[el * 260 + r * 8];
        const float* bp = bias + r * 8;
        float s = 0.f;
#pragma unroll
        for (int p = 0; p < 8; ++p) s += (dp[p] + bp[p]) * ue[p];
        t2l[l] = s;
      }
      ushort4 ov;
      ov.x = f2bf(t2l[0] * b2e[0] + t2l[1] * b2e[4]);
      ov.y = f2bf(t2l[0] * b2e[1] + t2l[1] * b2e[5]);
      ov.z = f2bf(t2l[0] * b2e[2] + t2l[1] * b2e[6]);
      ov.w = f2bf(t2l[0] * b2e[3] + t2l[1] * b2e[7]);
      *(ushort4*)&kv[e * 64 + m * 4] = ov;
    }
    __syncthreads();
  }
}

// ---------------- attention scores + segment denominator --------------------
// scores std ~0.08 => exp without max-subtraction is safe & mathematically equal
__global__ void score_kernel(const float* __restrict__ q, const u16* __restrict__ kv,
                             const int* __restrict__ dst, float* __restrict__ ex,
                             float* __restrict__ den) {
  int i = blockIdx.x * 256 + threadIdx.x;   // e*4 + h, grid exact
  int e = i >> 2, h = i & 3;
  int n = dst[e];
  const float* qn = q + (size_t)n * 64 + h * 16;
  const u16* ke = kv + (size_t)e * 64 + h * 16;
  float s = 0.f;
#pragma unroll
  for (int x = 0; x < 16; ++x) s += qn[x] * bf2f(ke[x]);
  float exv = expf(s * 0.25f);              // scale = sqrt(HM*DIM) = 4
  ex[i] = exv;
  atomicAdd(&den[n * 4 + h], exv);
}

// ---------------- weighted scatter of V -------------------------------------
__global__ void out_kernel(const float* __restrict__ ex, const float* __restrict__ den,
                           const u16* __restrict__ kv, const int* __restrict__ dst,
                           float* __restrict__ outp) {
  int i = blockIdx.x * 256 + threadIdx.x;   // e*16 + m, grid exact
  int e = i >> 4, m = i & 15, h = m >> 2;
  int n = dst[e];
  float alpha = ex[e * 4 + h] / fmaxf(den[n * 4 + h], 1e-9f);
  const u16* ve = kv + (size_t)e * 64 + m * 4;
  float* op = outp + (size_t)n * 64 + m * 4;
#pragma unroll
  for (int d = 0; d < 4; ++d) atomicAdd(&op[d], alpha * bf2f(ve[d]));
}

extern "C" void kernel_launch(void* const* d_in, const int* in_sizes, int n_in,
                              void* d_out, int out_size, void* d_ws, size_t ws_size,
                              hipStream_t stream) {
  const float* b1  = (const float*)d_in[0];
  const float* b2  = (const float*)d_in[1];
  const float* ef  = (const float*)d_in[2];
  const float* f   = (const float*)d_in[3];
  const int*   src = (const int*)d_in[4];
  const int*   dst = (const int*)d_in[5];
  const float* qw  = (const float*)d_in[6];
  const float* qb  = (const float*)d_in[7];
  const float* kw1 = (const float*)d_in[8];
  const float* kb1 = (const float*)d_in[9];
  const float* kwl = (const float*)d_in[10];
  const float* kbl = (const float*)d_in[11];
  const float* kwr = (const float*)d_in[12];
  const float* kbr = (const float*)d_in[13];
  const float* vw1 = (const float*)d_in[14];
  const float* vb1 = (const float*)d_in[15];
  const float* vwl = (const float*)d_in[16];
  const float* vbl = (const float*)d_in[17];
  const float* vwr = (const float*)d_in[18];
  const float* vbr = (const float*)d_in[19];
  float* outp = (float*)d_out;

  // workspace layout (~103 MB total)
  char* ws = (char*)d_ws;
  size_t off = 0;
  auto alloc = [&](size_t bytes) {
    char* p = ws + off;
    off += (bytes + 511) & ~(size_t)511;
    return p;
  };
  u16*   Hbuf = (u16*)  alloc((size_t)NEDGE * 128 * 2);  // reused per conv
  u16*   Wsw  = (u16*)  alloc((size_t)4 * 32768 * 2);
  u16*   tbuf = (u16*)  alloc((size_t)NEDGE * 32 * 2);
  float* ubuf = (float*)alloc((size_t)NEDGE * 8 * 4);    // reused per conv
  u16*   kvk  = (u16*)  alloc((size_t)NEDGE * 64 * 2);
  u16*   kvv  = (u16*)  alloc((size_t)NEDGE * 64 * 2);
  float* qbuf = (float*)alloc((size_t)NNODES * 64 * 4);
  float* exb  = (float*)alloc((size_t)NEDGE * 4 * 4);
  float* den  = (float*)alloc((size_t)NNODES * 4 * 4);

  zero_kernel<<<2500, 256, 0, stream>>>(outp, den);
  prep_w_kernel<<<512, 256, 0, stream>>>(kwr, kwl, vwr, vwl, Wsw);
  q_kernel<<<625, 256, 0, stream>>>(f, qw, qb, qbuf);
  t_kernel<<<625, 256, 0, stream>>>(f, b1, src, tbuf);

  // conv K
  h_kernel<<<5000, 256, 0, stream>>>(ef, kw1, kb1, Hbuf);
  gemm_right_kernel<<<2500, 256, 0, stream>>>(Hbuf, Wsw + 0 * 32768, kbr, tbuf, ubuf);
  gemm_left_kernel<<<2500, 256, 0, stream>>>(Hbuf, Wsw + 1 * 32768, kbl, ubuf, b2, kvk);
  // conv V
  h_kernel<<<5000, 256, 0, stream>>>(ef, vw1, vb1, Hbuf);
  gemm_right_kernel<<<2500, 256, 0, stream>>>(Hbuf, Wsw + 2 * 32768, vbr, tbuf, ubuf);
  gemm_left_kernel<<<2500, 256, 0, stream>>>(Hbuf, Wsw + 3 * 32768, vbl, ubuf, b2, kvv);

  // attention
  score_kernel<<<2500, 256, 0, stream>>>(qbuf, kvk, dst, exb, den);
  out_kernel<<<10000, 256, 0, stream>>>(exb, den, kvv, dst, outp);
}

// Round 2
// 490.324 us; speedup vs baseline: 8.3903x; 8.3903x over previous
//
#include <hip/hip_runtime.h>
#include <hip/hip_bf16.h>
#include <math.h>

// Problem constants
#define NNODES 10000
#define NEDGE  160000
// MULT=16, NL=2, DIM=4, EDGE_DIM=32, HID=128, RANK=8, H=4, HM=4

typedef unsigned short u16;
using bf16x8 = __attribute__((ext_vector_type(8))) short;
using u16x8  = __attribute__((ext_vector_type(8))) unsigned short;
using f32x4  = __attribute__((ext_vector_type(4))) float;

static __device__ __forceinline__ u16 f2bf(float x) {
  unsigned u = __float_as_uint(x);
  u += 0x7FFFu + ((u >> 16) & 1u);     // RNE
  return (u16)(u >> 16);
}
static __device__ __forceinline__ float bf2f(u16 h) {
  return __uint_as_float(((unsigned)h) << 16);
}

// ---------------- zero init (harness poisons d_out/d_ws with 0xAA) ----------
__global__ void zero_kernel(float* __restrict__ outp, float* __restrict__ den) {
  int i = blockIdx.x * 256 + threadIdx.x;
  if (i < NNODES * 64) outp[i] = 0.0f;
  if (i < NNODES * 4)  den[i]  = 0.0f;
}

// ---------------- weight swizzle: (128,256) fp32 -> B-frag-major bf16 -------
// Wsw element at ((ntg*4+ks)*64 + lane)*8 + j  ==  W[k][col],
//   k = ks*32 + (lane>>4)*8 + j, col = ntg*16 + (lane&15)
// so a wave's 64 lanes read one contiguous 1 KiB line per B fragment.
__global__ void prep_w_kernel(const float* __restrict__ kwr, const float* __restrict__ kwl,
                              const float* __restrict__ vwr, const float* __restrict__ vwl,
                              u16* __restrict__ Wsw) {
  int idx = blockIdx.x * 256 + threadIdx.x;      // 0..131071  (4 slots x 32768)
  int slot = idx >> 15;
  int w = idx & 32767;
  int j = w & 7, lane = (w >> 3) & 63, ks = (w >> 9) & 3, ntg = w >> 11;
  int k   = ks * 32 + ((lane >> 4) << 3) + j;
  int col = (ntg << 4) + (lane & 15);
  const float* s = (slot == 0) ? kwr : (slot == 1) ? kwl : (slot == 2) ? vwr : vwl;
  Wsw[idx] = f2bf(s[k * 256 + col]);
}

// ---------------- w1 swizzle: (32,128) fp32 -> B-frag-major bf16 ------------
// W1sw[slot*4096 + (nt*64+lane)*8 + j] = w1[(lane>>4)*8+j][nt*16 + (lane&15)]
__global__ void prep_w1_kernel(const float* __restrict__ kw1, const float* __restrict__ vw1,
                               u16* __restrict__ W1sw) {
  int idx = blockIdx.x * 256 + threadIdx.x;      // 0..8191 (2 slots x 4096)
  int slot = idx >> 12;
  int w = idx & 4095;
  int j = w & 7, lane = (w >> 3) & 63, nt = w >> 9;
  int k   = ((lane >> 4) << 3) + j;
  int col = (nt << 4) + (lane & 15);
  const float* s = (slot == 0) ? kw1 : vw1;
  W1sw[idx] = f2bf(s[k * 128 + col]);
}

// ---------------- Q: equivariant linear (fp32, tiny) ------------------------
__global__ void q_kernel(const float* __restrict__ f, const float* __restrict__ qw,
                         const float* __restrict__ qb, float* __restrict__ q) {
  int i = blockIdx.x * 256 + threadIdx.x;        // n*16 + o
  if (i >= NNODES * 16) return;
  int n = i >> 4, o = i & 15;
  const float* frow = f + (size_t)n * 64;
  float o0 = 0.f, o1 = 0.f, o2 = 0.f, o3 = 0.f;
#pragma unroll
  for (int m = 0; m < 16; ++m) {
    float w0 = qw[o * 16 + m];          // irrep block 0 (d = 0)
    float w1 = qw[(16 + o) * 16 + m];   // irrep block 1 (d = 1..3)
    o0 += w0 * frow[m * 4 + 0];
    o1 += w1 * frow[m * 4 + 1];
    o2 += w1 * frow[m * 4 + 2];
    o3 += w1 * frow[m * 4 + 3];
  }
  o0 += qb[o];
  float4 r = make_float4(o0, o1, o2, o3);
  *(float4*)(q + (size_t)i * 4) = r;
}

// ---------------- t: basis contraction (shared by both convs) ---------------
__global__ void t_kernel(const float* __restrict__ f, const float* __restrict__ b1,
                         const int* __restrict__ src, u16* __restrict__ tbuf) {
  int e = blockIdx.x * 256 + threadIdx.x;        // grid covers exactly NEDGE
  const float* frow = f + (size_t)src[e] * 64;
  const float* be = b1 + (size_t)e * 8;          // (4,2)
  float b[8];
#pragma unroll
  for (int i = 0; i < 8; ++i) b[i] = be[i];
  u16* tp = tbuf + (size_t)e * 32;
#pragma unroll
  for (int m = 0; m < 16; ++m) {
    float f0 = frow[m * 4 + 0], f1 = frow[m * 4 + 1], f2 = frow[m * 4 + 2], f3 = frow[m * 4 + 3];
#pragma unroll
    for (int l = 0; l < 2; ++l) {
      float t = f0 * b[0 * 2 + l] + f1 * b[1 * 2 + l] + f2 * b[2 * 2 + l] + f3 * b[3 * 2 + l];
      tp[m * 2 + l] = f2bf(t);
    }
  }
}

// ---------------- radial hidden layer via MFMA ------------------------------
// H = gelu(EF @ w1 + b1) -> bf16. Per block: 64 edges. Wave w owns m-tile w
// (16 edges), computes all 8 n-tiles with ONE mfma each (K=32 = one step).
// Epilogue via padded LDS -> fully coalesced 16B/lane stores.
__global__ void __launch_bounds__(256) h_mfma_kernel(
    const float* __restrict__ ef, const u16* __restrict__ w1sw,
    const float* __restrict__ b1h, u16* __restrict__ H) {
  __shared__ float sD[64 * 132];
  int tid = threadIdx.x;
  int wave = tid >> 6, lane = tid & 63, quad = lane >> 4, l16 = lane & 15;
  size_t e0 = (size_t)blockIdx.x * 64;

  // A fragment: ef[e0 + wave*16 + l16][quad*8 .. +7] -> bf16x8 (coalesced 32B/lane)
  const float* ap = ef + (e0 + (size_t)(wave * 16 + l16)) * 32 + quad * 8;
  float av[8];
  *(float4*)&av[0] = *(const float4*)&ap[0];
  *(float4*)&av[4] = *(const float4*)&ap[4];
  bf16x8 a;
#pragma unroll
  for (int j = 0; j < 8; ++j) a[j] = (short)f2bf(av[j]);

  f32x4 acc[8];
#pragma unroll
  for (int nt = 0; nt < 8; ++nt) {
    bf16x8 b = *(const bf16x8*)&w1sw[(size_t)(nt * 64 + lane) * 8];
    acc[nt] = __builtin_amdgcn_mfma_f32_16x16x32_bf16(a, b, (f32x4){0.f, 0.f, 0.f, 0.f}, 0, 0, 0);
  }

  // dump to LDS: row = wave*16 + quad*4 + r, col = nt*16 + l16 (2-way alias = free)
#pragma unroll
  for (int nt = 0; nt < 8; ++nt)
#pragma unroll
    for (int r = 0; r < 4; ++r)
      sD[(wave * 16 + quad * 4 + r) * 132 + nt * 16 + l16] = acc[nt][r];
  __syncthreads();

  // epilogue: bias + gelu + pack; wave writes contiguous 1 KiB per iteration
#pragma unroll
  for (int it = 0; it < 4; ++it) {
    int idx = it * 2048 + tid * 8;
    int row = idx >> 7, col = idx & 127;
    const float* dp = &sD[row * 132 + col];
    const float* bp = &b1h[col];
    u16x8 ov;
#pragma unroll
    for (int j = 0; j < 8; ++j) {
      float x = dp[j] + bp[j];
      float g = 0.5f * x * (1.0f + erff(x * 0.7071067811865475f)); // exact gelu
      ov[j] = f2bf(g);
    }
    *(u16x8*)&H[(e0 + (size_t)row) * 128 + col] = ov;
  }
}

// ---------------- MFMA GEMM core macro: 64 edges x 256 cols x K=128 ---------
#define GEMM_CORE()                                                                  \
  int tid = threadIdx.x;                                                             \
  int wave = tid >> 6, lane = tid & 63, quad = lane >> 4, l16 = lane & 15;           \
  size_t e0 = (size_t)blockIdx.x * 64;                                               \
  for (int c = tid; c < 1024; c += 256) {                                            \
    int row = c >> 4, off = (c & 15) << 3;                                           \
    *(uint4*)&sA[row * 136 + off] = *(const uint4*)&H[(e0 + row) * 128 + off];       \
  }                                                                                  \
  __syncthreads();                                                                   \
  f32x4 acc[4][4];                                                                   \
  _Pragma("unroll") for (int mt = 0; mt < 4; ++mt)                                   \
    _Pragma("unroll") for (int nt = 0; nt < 4; ++nt)                                 \
      acc[mt][nt] = (f32x4){0.f, 0.f, 0.f, 0.f};                                     \
  _Pragma("unroll") for (int ks = 0; ks < 4; ++ks) {                                 \
    bf16x8 a[4], b[4];                                                               \
    _Pragma("unroll") for (int mt = 0; mt < 4; ++mt)                                 \
      a[mt] = *(const bf16x8*)&sA[(mt * 16 + l16) * 136 + ks * 32 + quad * 8];       \
    _Pragma("unroll") for (int nt = 0; nt < 4; ++nt)                                 \
      b[nt] = *(const bf16x8*)&Wsw[(size_t)(((wave * 4 + nt) * 4 + ks) * 64 + lane) * 8]; \
    _Pragma("unroll") for (int mt = 0; mt < 4; ++mt)                                 \
      _Pragma("unroll") for (int nt = 0; nt < 4; ++nt)                               \
        acc[mt][nt] = __builtin_amdgcn_mfma_f32_16x16x32_bf16(a[mt], b[nt],          \
                                                              acc[mt][nt], 0, 0, 0); \
  }

#define DUMP_MT(mt)                                                                  \
  _Pragma("unroll") for (int nt = 0; nt < 4; ++nt) {                                 \
    int colg = (wave * 4 + nt) * 16 + l16;                                           \
    _Pragma("unroll") for (int r = 0; r < 4; ++r)                                    \
      sD[(quad * 4 + r) * 260 + colg] = acc[mt][nt][r];                              \
  }

// GEMM-R: right = H @ wr + br ; epilogue u[e][p] = sum_c right[e][p*32+c]*t[e][c]
__global__ void __launch_bounds__(256) gemm_right_kernel(
    const u16* __restrict__ H, const u16* __restrict__ Wsw,
    const float* __restrict__ bias, const u16* __restrict__ tbuf,
    float* __restrict__ ubuf) {
  __shared__ alignas(16) u16 sA[64 * 136];
  __shared__ float sD[16 * 260];
  GEMM_CORE()
#pragma unroll
  for (int mt = 0; mt < 4; ++mt) {
    DUMP_MT(mt)
    __syncthreads();
    if (tid < 128) {
      int el = tid >> 3, p = tid & 7;
      size_t e = e0 + mt * 16 + el;
      const u16* te = tbuf + e * 32;
      const float* bp = bias + p * 32;
      const float* dp = &sD[el * 260 + p * 32];
      float s = 0.f;
#pragma unroll
      for (int c = 0; c < 32; ++c) s += (dp[c] + bp[c]) * bf2f(te[c]);
      ubuf[e * 8 + p] = s;
    }
    __syncthreads();
  }
}

// GEMM-L: left = H @ wl + bl ; epilogue t2[r]=sum_p left[r*8+p]*u[p];
// out[e][m][d] = t2[m*2+0]*b2[e][0][d] + t2[m*2+1]*b2[e][1][d]  -> bf16
__global__ void __launch_bounds__(256) gemm_left_kernel(
    const u16* __restrict__ H, const u16* __restrict__ Wsw,
    const float* __restrict__ bias, const float* __restrict__ ubuf,
    const float* __restrict__ b2, u16* __restrict__ kv) {
  __shared__ alignas(16) u16 sA[64 * 136];
  __shared__ float sD[16 * 260];
  GEMM_CORE()
#pragma unroll
  for (int mt = 0; mt < 4; ++mt) {
    DUMP_MT(mt)
    __syncthreads();
    {
      int el = tid >> 4, m = tid & 15;
      size_t e = e0 + mt * 16 + el;
      const float* ue = ubuf + e * 8;
      const float* b2e = b2 + e * 8;   // (2,4)
      float t2l[2];
#pragma unroll
      for (int l = 0; l < 2; ++l) {
        int r = m * 2 + l;
        const float* dp = &sD[el * 260 + r * 8];
        const float* bp = bias + r * 8;
        float s = 0.f;
#pragma unroll
        for (int p = 0; p < 8; ++p) s += (dp[p] + bp[p]) * ue[p];
        t2l[l] = s;
      }
      ushort4 ov;
      ov.x = f2bf(t2l[0] * b2e[0] + t2l[1] * b2e[4]);
      ov.y = f2bf(t2l[0] * b2e[1] + t2l[1] * b2e[5]);
      ov.z = f2bf(t2l[0] * b2e[2] + t2l[1] * b2e[6]);
      ov.w = f2bf(t2l[0] * b2e[3] + t2l[1] * b2e[7]);
      *(ushort4*)&kv[e * 64 + m * 4] = ov;
    }
    __syncthreads();
  }
}

// ---------------- attention scores + segment denominator --------------------
// scores std ~0.08 => exp without max-subtraction is safe & mathematically equal
__global__ void score_kernel(const float* __restrict__ q, const u16* __restrict__ kv,
                             const int* __restrict__ dst, float* __restrict__ ex,
                             float* __restrict__ den) {
  int i = blockIdx.x * 256 + threadIdx.x;   // e*4 + h, grid exact
  int e = i >> 2, h = i & 3;
  int n = dst[e];
  const float* qn = q + (size_t)n * 64 + h * 16;
  const u16* ke = kv + (size_t)e * 64 + h * 16;
  float s = 0.f;
#pragma unroll
  for (int x = 0; x < 16; ++x) s += qn[x] * bf2f(ke[x]);
  float exv = expf(s * 0.25f);              // scale = sqrt(HM*DIM) = 4
  ex[i] = exv;
  atomicAdd(&den[n * 4 + h], exv);
}

// ---------------- weighted scatter of V -------------------------------------
__global__ void out_kernel(const float* __restrict__ ex, const float* __restrict__ den,
                           const u16* __restrict__ kv, const int* __restrict__ dst,
                           float* __restrict__ outp) {
  int i = blockIdx.x * 256 + threadIdx.x;   // e*16 + m, grid exact
  int e = i >> 4, m = i & 15, h = m >> 2;
  int n = dst[e];
  float alpha = ex[e * 4 + h] / fmaxf(den[n * 4 + h], 1e-9f);
  const u16* ve = kv + (size_t)e * 64 + m * 4;
  float* op = outp + (size_t)n * 64 + m * 4;
#pragma unroll
  for (int d = 0; d < 4; ++d) atomicAdd(&op[d], alpha * bf2f(ve[d]));
}

extern "C" void kernel_launch(void* const* d_in, const int* in_sizes, int n_in,
                              void* d_out, int out_size, void* d_ws, size_t ws_size,
                              hipStream_t stream) {
  const float* b1  = (const float*)d_in[0];
  const float* b2  = (const float*)d_in[1];
  const float* ef  = (const float*)d_in[2];
  const float* f   = (const float*)d_in[3];
  const int*   src = (const int*)d_in[4];
  const int*   dst = (const int*)d_in[5];
  const float* qw  = (const float*)d_in[6];
  const float* qb  = (const float*)d_in[7];
  const float* kw1 = (const float*)d_in[8];
  const float* kb1 = (const float*)d_in[9];
  const float* kwl = (const float*)d_in[10];
  const float* kbl = (const float*)d_in[11];
  const float* kwr = (const float*)d_in[12];
  const float* kbr = (const float*)d_in[13];
  const float* vw1 = (const float*)d_in[14];
  const float* vb1 = (const float*)d_in[15];
  const float* vwl = (const float*)d_in[16];
  const float* vbl = (const float*)d_in[17];
  const float* vwr = (const float*)d_in[18];
  const float* vbr = (const float*)d_in[19];
  float* outp = (float*)d_out;

  // workspace layout (~103 MB total)
  char* ws = (char*)d_ws;
  size_t off = 0;
  auto alloc = [&](size_t bytes) {
    char* p = ws + off;
    off += (bytes + 511) & ~(size_t)511;
    return p;
  };
  u16*   Hbuf = (u16*)  alloc((size_t)NEDGE * 128 * 2);  // reused per conv
  u16*   Wsw  = (u16*)  alloc((size_t)4 * 32768 * 2);
  u16*   W1sw = (u16*)  alloc((size_t)2 * 4096 * 2);
  u16*   tbuf = (u16*)  alloc((size_t)NEDGE * 32 * 2);
  float* ubuf = (float*)alloc((size_t)NEDGE * 8 * 4);    // reused per conv
  u16*   kvk  = (u16*)  alloc((size_t)NEDGE * 64 * 2);
  u16*   kvv  = (u16*)  alloc((size_t)NEDGE * 64 * 2);
  float* qbuf = (float*)alloc((size_t)NNODES * 64 * 4);
  float* exb  = (float*)alloc((size_t)NEDGE * 4 * 4);
  float* den  = (float*)alloc((size_t)NNODES * 4 * 4);

  zero_kernel<<<2500, 256, 0, stream>>>(outp, den);
  prep_w_kernel<<<512, 256, 0, stream>>>(kwr, kwl, vwr, vwl, Wsw);
  prep_w1_kernel<<<32, 256, 0, stream>>>(kw1, vw1, W1sw);
  q_kernel<<<625, 256, 0, stream>>>(f, qw, qb, qbuf);
  t_kernel<<<625, 256, 0, stream>>>(f, b1, src, tbuf);

  // conv K
  h_mfma_kernel<<<2500, 256, 0, stream>>>(ef, W1sw + 0 * 4096, kb1, Hbuf);
  gemm_right_kernel<<<2500, 256, 0, stream>>>(Hbuf, Wsw + 0 * 32768, kbr, tbuf, ubuf);
  gemm_left_kernel<<<2500, 256, 0, stream>>>(Hbuf, Wsw + 1 * 32768, kbl, ubuf, b2, kvk);
  // conv V
  h_mfma_kernel<<<2500, 256, 0, stream>>>(ef, W1sw + 1 * 4096, vb1, Hbuf);
  gemm_right_kernel<<<2500, 256, 0, stream>>>(Hbuf, Wsw + 2 * 32768, vbr, tbuf, ubuf);
  gemm_left_kernel<<<2500, 256, 0, stream>>>(Hbuf, Wsw + 3 * 32768, vbl, ubuf, b2, kvv);

  // attention
  score_kernel<<<2500, 256, 0, stream>>>(qbuf, kvk, dst, exb, den);
  out_kernel<<<10000, 256, 0, stream>>>(exb, den, kvv, dst, outp);
}

// Round 3
// 418.423 us; speedup vs baseline: 9.8321x; 1.1718x over previous
//
#include <hip/hip_runtime.h>
#include <hip/hip_bf16.h>
#include <math.h>

// Problem constants
#define NNODES 10000
#define NEDGE  160000
// MULT=16, NL=2, DIM=4, EDGE_DIM=32, HID=128, RANK=8, H=4, HM=4

typedef unsigned short u16;
using bf16x8 = __attribute__((ext_vector_type(8))) short;
using u16x8  = __attribute__((ext_vector_type(8))) unsigned short;
using f32x4  = __attribute__((ext_vector_type(4))) float;

static __device__ __forceinline__ u16 f2bf(float x) {
  unsigned u = __float_as_uint(x);
  u += 0x7FFFu + ((u >> 16) & 1u);     // RNE
  return (u16)(u >> 16);
}
static __device__ __forceinline__ float bf2f(u16 h) {
  return __uint_as_float(((unsigned)h) << 16);
}

// ---------------- weight swizzle: (128,256) fp32 -> B-frag-major bf16 -------
__global__ void prep_w_kernel(const float* __restrict__ kwr, const float* __restrict__ kwl,
                              const float* __restrict__ vwr, const float* __restrict__ vwl,
                              u16* __restrict__ Wsw) {
  int idx = blockIdx.x * 256 + threadIdx.x;      // 0..131071  (4 slots x 32768)
  int slot = idx >> 15;
  int w = idx & 32767;
  int j = w & 7, lane = (w >> 3) & 63, ks = (w >> 9) & 3, ntg = w >> 11;
  int k   = ks * 32 + ((lane >> 4) << 3) + j;
  int col = (ntg << 4) + (lane & 15);
  const float* s = (slot == 0) ? kwr : (slot == 1) ? kwl : (slot == 2) ? vwr : vwl;
  Wsw[idx] = f2bf(s[k * 256 + col]);
}

// ---------------- w1 swizzle: (32,128) fp32 -> B-frag-major bf16 ------------
__global__ void prep_w1_kernel(const float* __restrict__ kw1, const float* __restrict__ vw1,
                               u16* __restrict__ W1sw) {
  int idx = blockIdx.x * 256 + threadIdx.x;      // 0..8191 (2 slots x 4096)
  int slot = idx >> 12;
  int w = idx & 4095;
  int j = w & 7, lane = (w >> 3) & 63, nt = w >> 9;
  int k   = ((lane >> 4) << 3) + j;
  int col = (nt << 4) + (lane & 15);
  const float* s = (slot == 0) ? kw1 : vw1;
  W1sw[idx] = f2bf(s[k * 128 + col]);
}

// ---------------- CSR build: edges grouped by dst ---------------------------
__global__ void csr_zero_kernel(int* __restrict__ cnt) {
  int i = blockIdx.x * 256 + threadIdx.x;
  if (i < NNODES) cnt[i] = 0;
}
__global__ void csr_count_kernel(const int* __restrict__ dst, int* __restrict__ cnt) {
  int e = blockIdx.x * 256 + threadIdx.x;        // grid exact
  atomicAdd(&cnt[dst[e]], 1);
}
// single-block exclusive scan of 10000 counts -> rowptr[10001], cursor copy
__global__ void __launch_bounds__(256) csr_scan_kernel(
    const int* __restrict__ cnt, int* __restrict__ rowptr, int* __restrict__ cursor) {
  __shared__ int part[256];
  int t = threadIdx.x;
  int base = t * 40;                              // 256*40 = 10240 >= NNODES
  int s = 0;
#pragma unroll 8
  for (int i = 0; i < 40; ++i) { int idx = base + i; if (idx < NNODES) s += cnt[idx]; }
  part[t] = s;
  __syncthreads();
  for (int o = 1; o < 256; o <<= 1) {
    int v = (t >= o) ? part[t - o] : 0;
    __syncthreads();
    part[t] += v;
    __syncthreads();
  }
  int run = (t == 0) ? 0 : part[t - 1];
#pragma unroll 8
  for (int i = 0; i < 40; ++i) {
    int idx = base + i;
    if (idx < NNODES) { rowptr[idx] = run; cursor[idx] = run; run += cnt[idx]; }
  }
  if (t == 255) rowptr[NNODES] = run;
}
__global__ void csr_fill_kernel(const int* __restrict__ dst, int* __restrict__ cursor,
                                int* __restrict__ eidx) {
  int e = blockIdx.x * 256 + threadIdx.x;        // grid exact
  int pos = atomicAdd(&cursor[dst[e]], 1);
  eidx[pos] = e;
}

// ---------------- Q: equivariant linear (fp32, tiny) ------------------------
__global__ void q_kernel(const float* __restrict__ f, const float* __restrict__ qw,
                         const float* __restrict__ qb, float* __restrict__ q) {
  int i = blockIdx.x * 256 + threadIdx.x;        // n*16 + o
  if (i >= NNODES * 16) return;
  int n = i >> 4, o = i & 15;
  const float* frow = f + (size_t)n * 64;
  float o0 = 0.f, o1 = 0.f, o2 = 0.f, o3 = 0.f;
#pragma unroll
  for (int m = 0; m < 16; ++m) {
    float w0 = qw[o * 16 + m];          // irrep block 0 (d = 0)
    float w1 = qw[(16 + o) * 16 + m];   // irrep block 1 (d = 1..3)
    o0 += w0 * frow[m * 4 + 0];
    o1 += w1 * frow[m * 4 + 1];
    o2 += w1 * frow[m * 4 + 2];
    o3 += w1 * frow[m * 4 + 3];
  }
  o0 += qb[o];
  float4 r = make_float4(o0, o1, o2, o3);
  *(float4*)(q + (size_t)i * 4) = r;
}

// ---------------- t: basis contraction (shared by both convs) ---------------
__global__ void t_kernel(const float* __restrict__ f, const float* __restrict__ b1,
                         const int* __restrict__ src, u16* __restrict__ tbuf) {
  int e = blockIdx.x * 256 + threadIdx.x;        // grid covers exactly NEDGE
  const float* frow = f + (size_t)src[e] * 64;
  const float* be = b1 + (size_t)e * 8;          // (4,2)
  float b[8];
#pragma unroll
  for (int i = 0; i < 8; ++i) b[i] = be[i];
  u16* tp = tbuf + (size_t)e * 32;
#pragma unroll
  for (int mh = 0; mh < 4; ++mh) {               // 4 groups of 4 m -> u16x8 stores
    u16x8 ov;
#pragma unroll
    for (int mi = 0; mi < 4; ++mi) {
      int m = mh * 4 + mi;
      float f0 = frow[m * 4 + 0], f1 = frow[m * 4 + 1], f2 = frow[m * 4 + 2], f3 = frow[m * 4 + 3];
#pragma unroll
      for (int l = 0; l < 2; ++l) {
        float t = f0 * b[0 * 2 + l] + f1 * b[1 * 2 + l] + f2 * b[2 * 2 + l] + f3 * b[3 * 2 + l];
        ov[mi * 2 + l] = f2bf(t);
      }
    }
    *(u16x8*)&tp[mh * 8] = ov;
  }
}

// ---------------- radial hidden layer via MFMA ------------------------------
__global__ void __launch_bounds__(256) h_mfma_kernel(
    const float* __restrict__ ef, const u16* __restrict__ w1sw,
    const float* __restrict__ b1h, u16* __restrict__ H) {
  __shared__ float sD[64 * 132];
  int tid = threadIdx.x;
  int wave = tid >> 6, lane = tid & 63, quad = lane >> 4, l16 = lane & 15;
  size_t e0 = (size_t)blockIdx.x * 64;

  const float* ap = ef + (e0 + (size_t)(wave * 16 + l16)) * 32 + quad * 8;
  float av[8];
  *(float4*)&av[0] = *(const float4*)&ap[0];
  *(float4*)&av[4] = *(const float4*)&ap[4];
  bf16x8 a;
#pragma unroll
  for (int j = 0; j < 8; ++j) a[j] = (short)f2bf(av[j]);

  f32x4 acc[8];
#pragma unroll
  for (int nt = 0; nt < 8; ++nt) {
    bf16x8 b = *(const bf16x8*)&w1sw[(size_t)(nt * 64 + lane) * 8];
    acc[nt] = __builtin_amdgcn_mfma_f32_16x16x32_bf16(a, b, (f32x4){0.f, 0.f, 0.f, 0.f}, 0, 0, 0);
  }

#pragma unroll
  for (int nt = 0; nt < 8; ++nt)
#pragma unroll
    for (int r = 0; r < 4; ++r)
      sD[(wave * 16 + quad * 4 + r) * 132 + nt * 16 + l16] = acc[nt][r];
  __syncthreads();

#pragma unroll
  for (int it = 0; it < 4; ++it) {
    int idx = it * 2048 + tid * 8;
    int row = idx >> 7, col = idx & 127;
    const float* dp = &sD[row * 132 + col];
    const float* bp = &b1h[col];
    u16x8 ov;
#pragma unroll
    for (int j = 0; j < 8; ++j) {
      float x = dp[j] + bp[j];
      float g = 0.5f * x * (1.0f + erff(x * 0.7071067811865475f)); // exact gelu
      ov[j] = f2bf(g);
    }
    *(u16x8*)&H[(e0 + (size_t)row) * 128 + col] = ov;
  }
}

// ---------------- MFMA GEMM core macro: 64 edges x 256 cols x K=128 ---------
#define GEMM_CORE()                                                                  \
  int tid = threadIdx.x;                                                             \
  int wave = tid >> 6, lane = tid & 63, quad = lane >> 4, l16 = lane & 15;           \
  size_t e0 = (size_t)blockIdx.x * 64;                                               \
  for (int c = tid; c < 1024; c += 256) {                                            \
    int row = c >> 4, off = (c & 15) << 3;                                           \
    *(uint4*)&sA[row * 136 + off] = *(const uint4*)&H[(e0 + row) * 128 + off];       \
  }                                                                                  \
  __syncthreads();                                                                   \
  f32x4 acc[4][4];                                                                   \
  _Pragma("unroll") for (int mt = 0; mt < 4; ++mt)                                   \
    _Pragma("unroll") for (int nt = 0; nt < 4; ++nt)                                 \
      acc[mt][nt] = (f32x4){0.f, 0.f, 0.f, 0.f};                                     \
  _Pragma("unroll") for (int ks = 0; ks < 4; ++ks) {                                 \
    bf16x8 a[4], b[4];                                                               \
    _Pragma("unroll") for (int mt = 0; mt < 4; ++mt)                                 \
      a[mt] = *(const bf16x8*)&sA[(mt * 16 + l16) * 136 + ks * 32 + quad * 8];       \
    _Pragma("unroll") for (int nt = 0; nt < 4; ++nt)                                 \
      b[nt] = *(const bf16x8*)&Wsw[(size_t)(((wave * 4 + nt) * 4 + ks) * 64 + lane) * 8]; \
    _Pragma("unroll") for (int mt = 0; mt < 4; ++mt)                                 \
      _Pragma("unroll") for (int nt = 0; nt < 4; ++nt)                               \
        acc[mt][nt] = __builtin_amdgcn_mfma_f32_16x16x32_bf16(a[mt], b[nt],          \
                                                              acc[mt][nt], 0, 0, 0); \
  }

#define DUMP_MT(mt)                                                                  \
  _Pragma("unroll") for (int nt = 0; nt < 4; ++nt) {                                 \
    int colg = (wave * 4 + nt) * 16 + l16;                                           \
    _Pragma("unroll") for (int r = 0; r < 4; ++r)                                    \
      sD[(quad * 4 + r) * 260 + colg] = acc[mt][nt][r];                              \
  }

// GEMM-R: right = H @ wr + br ; epilogue u[e][p] = sum_c right[e][p*32+c]*t[e][c]
__global__ void __launch_bounds__(256) gemm_right_kernel(
    const u16* __restrict__ H, const u16* __restrict__ Wsw,
    const float* __restrict__ bias, const u16* __restrict__ tbuf,
    float* __restrict__ ubuf) {
  __shared__ alignas(16) u16 sA[64 * 136];
  __shared__ float sD[16 * 260];
  GEMM_CORE()
#pragma unroll
  for (int mt = 0; mt < 4; ++mt) {
    DUMP_MT(mt)
    __syncthreads();
    if (tid < 128) {
      int el = tid >> 3, p = tid & 7;
      size_t e = e0 + mt * 16 + el;
      const u16* te = tbuf + e * 32;
      const float* bp = bias + p * 32;
      const float* dp = &sD[el * 260 + p * 32];
      float s = 0.f;
#pragma unroll
      for (int c = 0; c < 32; ++c) s += (dp[c] + bp[c]) * bf2f(te[c]);
      ubuf[e * 8 + p] = s;
    }
    __syncthreads();
  }
}

// GEMM-L: left = H @ wl + bl ; epilogue t2[r]=sum_p left[r*8+p]*u[p];
// out[e][m][d] = t2[m*2+0]*b2[e][0][d] + t2[m*2+1]*b2[e][1][d]  -> bf16
__global__ void __launch_bounds__(256) gemm_left_kernel(
    const u16* __restrict__ H, const u16* __restrict__ Wsw,
    const float* __restrict__ bias, const float* __restrict__ ubuf,
    const float* __restrict__ b2, u16* __restrict__ kv) {
  __shared__ alignas(16) u16 sA[64 * 136];
  __shared__ float sD[16 * 260];
  GEMM_CORE()
#pragma unroll
  for (int mt = 0; mt < 4; ++mt) {
    DUMP_MT(mt)
    __syncthreads();
    {
      int el = tid >> 4, m = tid & 15;
      size_t e = e0 + mt * 16 + el;
      const float* ue = ubuf + e * 8;
      const float* b2e = b2 + e * 8;   // (2,4)
      float t2l[2];
#pragma unroll
      for (int l = 0; l < 2; ++l) {
        int r = m * 2 + l;
        const float* dp = &sD[el * 260 + r * 8];
        const float* bp = bias + r * 8;
        float s = 0.f;
#pragma unroll
        for (int p = 0; p < 8; ++p) s += (dp[p] + bp[p]) * ue[p];
        t2l[l] = s;
      }
      ushort4 ov;
      ov.x = f2bf(t2l[0] * b2e[0] + t2l[1] * b2e[4]);
      ov.y = f2bf(t2l[0] * b2e[1] + t2l[1] * b2e[5]);
      ov.z = f2bf(t2l[0] * b2e[2] + t2l[1] * b2e[6]);
      ov.w = f2bf(t2l[0] * b2e[3] + t2l[1] * b2e[7]);
      *(ushort4*)&kv[e * 64 + m * 4] = ov;
    }
    __syncthreads();
  }
}

// ---------------- fused attention gather (score + softmax + reduce) ---------
// One wave per node; lane l owns output element l (head = l>>4).
// Single pass: num += exp(s)*v, den += exp(s); out = num/den.
// exp without max-subtraction: scores ~N(0,0.1) -> no overflow, math identical.
__global__ void __launch_bounds__(256) attn_gather_kernel(
    const float* __restrict__ q, const u16* __restrict__ kvk,
    const u16* __restrict__ kvv, const int* __restrict__ rowptr,
    const int* __restrict__ eidx, float* __restrict__ outp) {
  int tid = threadIdx.x;
  int node = blockIdx.x * 4 + (tid >> 6);        // grid 2500 * 4 = NNODES
  int lane = tid & 63;
  float qv = q[(size_t)node * 64 + lane];
  int beg = rowptr[node], end = rowptr[node + 1];
  float num = 0.f, den = 0.f;
  for (int idx = beg; idx < end; ++idx) {
    int e = eidx[idx];
    float kf = bf2f(kvk[(size_t)e * 64 + lane]);
    float p = qv * kf;                            // head-dot via width-16 butterfly
    p += __shfl_xor(p, 1, 16);
    p += __shfl_xor(p, 2, 16);
    p += __shfl_xor(p, 4, 16);
    p += __shfl_xor(p, 8, 16);
    float exv = expf(p * 0.25f);                  // scale = sqrt(HM*DIM) = 4
    den += exv;
    num += exv * bf2f(kvv[(size_t)e * 64 + lane]);
  }
  outp[(size_t)node * 64 + lane] = num / fmaxf(den, 1e-9f);
}

extern "C" void kernel_launch(void* const* d_in, const int* in_sizes, int n_in,
                              void* d_out, int out_size, void* d_ws, size_t ws_size,
                              hipStream_t stream) {
  const float* b1  = (const float*)d_in[0];
  const float* b2  = (const float*)d_in[1];
  const float* ef  = (const float*)d_in[2];
  const float* f   = (const float*)d_in[3];
  const int*   src = (const int*)d_in[4];
  const int*   dst = (const int*)d_in[5];
  const float* qw  = (const float*)d_in[6];
  const float* qb  = (const float*)d_in[7];
  const float* kw1 = (const float*)d_in[8];
  const float* kb1 = (const float*)d_in[9];
  const float* kwl = (const float*)d_in[10];
  const float* kbl = (const float*)d_in[11];
  const float* kwr = (const float*)d_in[12];
  const float* kbr = (const float*)d_in[13];
  const float* vw1 = (const float*)d_in[14];
  const float* vb1 = (const float*)d_in[15];
  const float* vwl = (const float*)d_in[16];
  const float* vbl = (const float*)d_in[17];
  const float* vwr = (const float*)d_in[18];
  const float* vbr = (const float*)d_in[19];
  float* outp = (float*)d_out;

  // workspace layout
  char* ws = (char*)d_ws;
  size_t off = 0;
  auto alloc = [&](size_t bytes) {
    char* p = ws + off;
    off += (bytes + 511) & ~(size_t)511;
    return p;
  };
  u16*   Hbuf = (u16*)  alloc((size_t)NEDGE * 128 * 2);  // reused per conv
  u16*   Wsw  = (u16*)  alloc((size_t)4 * 32768 * 2);
  u16*   W1sw = (u16*)  alloc((size_t)2 * 4096 * 2);
  u16*   tbuf = (u16*)  alloc((size_t)NEDGE * 32 * 2);
  float* ubuf = (float*)alloc((size_t)NEDGE * 8 * 4);    // reused per conv
  u16*   kvk  = (u16*)  alloc((size_t)NEDGE * 64 * 2);
  u16*   kvv  = (u16*)  alloc((size_t)NEDGE * 64 * 2);
  float* qbuf = (float*)alloc((size_t)NNODES * 64 * 4);
  int*   cnt    = (int*)alloc((size_t)NNODES * 4);
  int*   rowptr = (int*)alloc((size_t)(NNODES + 1) * 4);
  int*   cursor = (int*)alloc((size_t)NNODES * 4);
  int*   eidx   = (int*)alloc((size_t)NEDGE * 4);

  // CSR build (independent of conv pipeline)
  csr_zero_kernel<<<40, 256, 0, stream>>>(cnt);
  csr_count_kernel<<<625, 256, 0, stream>>>(dst, cnt);
  csr_scan_kernel<<<1, 256, 0, stream>>>(cnt, rowptr, cursor);
  csr_fill_kernel<<<625, 256, 0, stream>>>(dst, cursor, eidx);

  prep_w_kernel<<<512, 256, 0, stream>>>(kwr, kwl, vwr, vwl, Wsw);
  prep_w1_kernel<<<32, 256, 0, stream>>>(kw1, vw1, W1sw);
  q_kernel<<<625, 256, 0, stream>>>(f, qw, qb, qbuf);
  t_kernel<<<625, 256, 0, stream>>>(f, b1, src, tbuf);

  // conv K
  h_mfma_kernel<<<2500, 256, 0, stream>>>(ef, W1sw + 0 * 4096, kb1, Hbuf);
  gemm_right_kernel<<<2500, 256, 0, stream>>>(Hbuf, Wsw + 0 * 32768, kbr, tbuf, ubuf);
  gemm_left_kernel<<<2500, 256, 0, stream>>>(Hbuf, Wsw + 1 * 32768, kbl, ubuf, b2, kvk);
  // conv V
  h_mfma_kernel<<<2500, 256, 0, stream>>>(ef, W1sw + 1 * 4096, vb1, Hbuf);
  gemm_right_kernel<<<2500, 256, 0, stream>>>(Hbuf, Wsw + 2 * 32768, vbr, tbuf, ubuf);
  gemm_left_kernel<<<2500, 256, 0, stream>>>(Hbuf, Wsw + 3 * 32768, vbl, ubuf, b2, kvv);

  // fused attention
  attn_gather_kernel<<<2500, 256, 0, stream>>>(qbuf, kvk, kvv, rowptr, eidx, outp);
}

// Round 4
// 380.685 us; speedup vs baseline: 10.8068x; 1.0991x over previous
//
#include <hip/hip_runtime.h>
#include <hip/hip_bf16.h>
#include <math.h>

// Problem constants
#define NNODES 10000
#define NEDGE  160000
// MULT=16, NL=2, DIM=4, EDGE_DIM=32, HID=128, RANK=8, H=4, HM=4

typedef unsigned short u16;
using bf16x8 = __attribute__((ext_vector_type(8))) short;
using u16x8  = __attribute__((ext_vector_type(8))) unsigned short;
using f32x4  = __attribute__((ext_vector_type(4))) float;

static __device__ __forceinline__ u16 f2bf(float x) {
  unsigned u = __float_as_uint(x);
  u += 0x7FFFu + ((u >> 16) & 1u);     // RNE
  return (u16)(u >> 16);
}
static __device__ __forceinline__ float bf2f(u16 h) {
  return __uint_as_float(((unsigned)h) << 16);
}

// ---------------- weight swizzle: (128,256) fp32 -> B-frag-major bf16 -------
// Wsw element at ((ntg*4+ks)*64 + lane)*8 + j  ==  W[k][col],
//   k = ks*32 + (lane>>4)*8 + j, col = ntg*16 + (lane&15)
__global__ void prep_w_kernel(const float* __restrict__ kwr, const float* __restrict__ kwl,
                              const float* __restrict__ vwr, const float* __restrict__ vwl,
                              u16* __restrict__ Wsw) {
  int idx = blockIdx.x * 256 + threadIdx.x;      // 0..131071  (4 slots x 32768)
  int slot = idx >> 15;
  int w = idx & 32767;
  int j = w & 7, lane = (w >> 3) & 63, ks = (w >> 9) & 3, ntg = w >> 11;
  int k   = ks * 32 + ((lane >> 4) << 3) + j;
  int col = (ntg << 4) + (lane & 15);
  const float* s = (slot == 0) ? kwr : (slot == 1) ? kwl : (slot == 2) ? vwr : vwl;
  Wsw[idx] = f2bf(s[k * 256 + col]);
}

// ---------------- w1 swizzle: (32,128) fp32 -> B-frag-major bf16 ------------
__global__ void prep_w1_kernel(const float* __restrict__ kw1, const float* __restrict__ vw1,
                               u16* __restrict__ W1sw) {
  int idx = blockIdx.x * 256 + threadIdx.x;      // 0..8191 (2 slots x 4096)
  int slot = idx >> 12;
  int w = idx & 4095;
  int j = w & 7, lane = (w >> 3) & 63, nt = w >> 9;
  int k   = ((lane >> 4) << 3) + j;
  int col = (nt << 4) + (lane & 15);
  const float* s = (slot == 0) ? kw1 : vw1;
  W1sw[idx] = f2bf(s[k * 128 + col]);
}

// ---------------- CSR build: edges grouped by dst ---------------------------
__global__ void csr_zero_kernel(int* __restrict__ cnt) {
  int i = blockIdx.x * 256 + threadIdx.x;
  if (i < NNODES) cnt[i] = 0;
}
__global__ void csr_count_kernel(const int* __restrict__ dst, int* __restrict__ cnt) {
  int e = blockIdx.x * 256 + threadIdx.x;        // grid exact
  atomicAdd(&cnt[dst[e]], 1);
}
__global__ void __launch_bounds__(256) csr_scan_kernel(
    const int* __restrict__ cnt, int* __restrict__ rowptr, int* __restrict__ cursor) {
  __shared__ int part[256];
  int t = threadIdx.x;
  int base = t * 40;                              // 256*40 = 10240 >= NNODES
  int s = 0;
#pragma unroll 8
  for (int i = 0; i < 40; ++i) { int idx = base + i; if (idx < NNODES) s += cnt[idx]; }
  part[t] = s;
  __syncthreads();
  for (int o = 1; o < 256; o <<= 1) {
    int v = (t >= o) ? part[t - o] : 0;
    __syncthreads();
    part[t] += v;
    __syncthreads();
  }
  int run = (t == 0) ? 0 : part[t - 1];
#pragma unroll 8
  for (int i = 0; i < 40; ++i) {
    int idx = base + i;
    if (idx < NNODES) { rowptr[idx] = run; cursor[idx] = run; run += cnt[idx]; }
  }
  if (t == 255) rowptr[NNODES] = run;
}
__global__ void csr_fill_kernel(const int* __restrict__ dst, int* __restrict__ cursor,
                                int* __restrict__ eidx) {
  int e = blockIdx.x * 256 + threadIdx.x;        // grid exact
  int pos = atomicAdd(&cursor[dst[e]], 1);
  eidx[pos] = e;
}

// ---------------- Q: equivariant linear (fp32, tiny) ------------------------
__global__ void q_kernel(const float* __restrict__ f, const float* __restrict__ qw,
                         const float* __restrict__ qb, float* __restrict__ q) {
  int i = blockIdx.x * 256 + threadIdx.x;        // n*16 + o
  if (i >= NNODES * 16) return;
  int n = i >> 4, o = i & 15;
  const float* frow = f + (size_t)n * 64;
  float o0 = 0.f, o1 = 0.f, o2 = 0.f, o3 = 0.f;
#pragma unroll
  for (int m = 0; m < 16; ++m) {
    float w0 = qw[o * 16 + m];          // irrep block 0 (d = 0)
    float w1 = qw[(16 + o) * 16 + m];   // irrep block 1 (d = 1..3)
    o0 += w0 * frow[m * 4 + 0];
    o1 += w1 * frow[m * 4 + 1];
    o2 += w1 * frow[m * 4 + 2];
    o3 += w1 * frow[m * 4 + 3];
  }
  o0 += qb[o];
  float4 r = make_float4(o0, o1, o2, o3);
  *(float4*)(q + (size_t)i * 4) = r;
}

// ---------------- t: basis contraction (shared by both convs) ---------------
__global__ void t_kernel(const float* __restrict__ f, const float* __restrict__ b1,
                         const int* __restrict__ src, u16* __restrict__ tbuf) {
  int e = blockIdx.x * 256 + threadIdx.x;        // grid covers exactly NEDGE
  const float* frow = f + (size_t)src[e] * 64;
  const float* be = b1 + (size_t)e * 8;          // (4,2)
  float b[8];
#pragma unroll
  for (int i = 0; i < 8; ++i) b[i] = be[i];
  u16* tp = tbuf + (size_t)e * 32;
#pragma unroll
  for (int mh = 0; mh < 4; ++mh) {               // 4 groups of 4 m -> u16x8 stores
    u16x8 ov;
#pragma unroll
    for (int mi = 0; mi < 4; ++mi) {
      int m = mh * 4 + mi;
      float f0 = frow[m * 4 + 0], f1 = frow[m * 4 + 1], f2 = frow[m * 4 + 2], f3 = frow[m * 4 + 3];
#pragma unroll
      for (int l = 0; l < 2; ++l) {
        float t = f0 * b[0 * 2 + l] + f1 * b[1 * 2 + l] + f2 * b[2 * 2 + l] + f3 * b[3 * 2 + l];
        ov[mi * 2 + l] = f2bf(t);
      }
    }
    *(u16x8*)&tp[mh * 8] = ov;
  }
}

// ---------------- fused equivariant conv: one kernel per conv ---------------
// Per 64-edge block (512 threads = 8 waves):
//  stage A: t-tile & b2-tile -> LDS; h-stage: gelu(ef@w1) via MFMA -> sA (bf16)
//  stage B: K-loop: both GEMMs (H@wr, H@wl) off sA; acc in regs
//  stage C: right epilogue: u[e,p] via width-16 shfl butterfly -> u_s
//  stage D: left epilogue: t2 via width-8 butterfly; kv = t2 . b2 -> kv_s
//  stage E: coalesced kv writeout
// Wave w owns n-tiles {2w, 2w+1} of each gemm => cols [w*32, w*32+32) =
// exactly p-group w (right) and r2-groups 4w..4w+3 => m in {2w, 2w+1} (left).
__global__ void __launch_bounds__(512, 4) conv_fused_kernel(
    const float* __restrict__ ef, const u16* __restrict__ w1sw,
    const float* __restrict__ b1h,
    const u16* __restrict__ wsw_r, const float* __restrict__ br,
    const u16* __restrict__ wsw_l, const float* __restrict__ bl,
    const u16* __restrict__ tbuf, const float* __restrict__ b2,
    u16* __restrict__ kv) {
  __shared__ alignas(16) u16 sA[64 * 136];   // H tile (bf16); later overlaid by kv_s[64*72]
  __shared__ alignas(16) u16 t_s[64 * 40];   // t tile
  __shared__ float u_s[64 * 9];              // u[row][p] (pad 9)
  __shared__ float b2_s[64 * 8];             // b2 tile

  int tid = threadIdx.x;
  int wave = tid >> 6, lane = tid & 63, quad = lane >> 4, l16 = lane & 15;
  size_t e0 = (size_t)blockIdx.x * 64;

  // ---- stage tiles ----
  if (tid < 256) {            // t tile: 64 rows x 32 u16
    int row = tid >> 2, seg = tid & 3;
    *(uint4*)&t_s[row * 40 + seg * 8] = *(const uint4*)&tbuf[(e0 + row) * 32 + seg * 8];
  } else if (tid < 384) {     // b2 tile: 64 rows x 8 f32
    int j = tid - 256, row = j >> 1, half = j & 1;
    *(float4*)&b2_s[row * 8 + half * 4] = *(const float4*)&b2[(e0 + row) * 8 + half * 4];
  }

  // ---- h-stage: H = gelu(ef @ w1 + b1) -> sA ----
  {
    int mt_h = wave & 3, ng = wave >> 2;
    const float* ap = ef + (e0 + (size_t)(mt_h * 16 + l16)) * 32 + quad * 8;
    float av[8];
    *(float4*)&av[0] = *(const float4*)&ap[0];
    *(float4*)&av[4] = *(const float4*)&ap[4];
    bf16x8 a;
#pragma unroll
    for (int j = 0; j < 8; ++j) a[j] = (short)f2bf(av[j]);
#pragma unroll
    for (int i = 0; i < 4; ++i) {
      int nt_h = ng * 4 + i;
      bf16x8 b = *(const bf16x8*)&w1sw[(size_t)(nt_h * 64 + lane) * 8];
      f32x4 acch = __builtin_amdgcn_mfma_f32_16x16x32_bf16(a, b, (f32x4){0.f, 0.f, 0.f, 0.f}, 0, 0, 0);
      int col = nt_h * 16 + l16;
      float bias = b1h[col];
#pragma unroll
      for (int r = 0; r < 4; ++r) {
        float x = acch[r] + bias;
        float g = 0.5f * x * (1.0f + erff(x * 0.7071067811865475f)); // exact gelu
        sA[(mt_h * 16 + quad * 4 + r) * 136 + col] = f2bf(g);
      }
    }
  }
  __syncthreads();

  // ---- K-loop: both GEMMs ----
  f32x4 accr[4][2], accl[4][2];
#pragma unroll
  for (int mt = 0; mt < 4; ++mt)
#pragma unroll
    for (int nt = 0; nt < 2; ++nt) {
      accr[mt][nt] = (f32x4){0.f, 0.f, 0.f, 0.f};
      accl[mt][nt] = (f32x4){0.f, 0.f, 0.f, 0.f};
    }
#pragma unroll
  for (int ks = 0; ks < 4; ++ks) {
    bf16x8 a[4];
#pragma unroll
    for (int mt = 0; mt < 4; ++mt)
      a[mt] = *(const bf16x8*)&sA[(mt * 16 + l16) * 136 + ks * 32 + quad * 8];
#pragma unroll
    for (int nt = 0; nt < 2; ++nt) {
      int ntg = wave * 2 + nt;
      bf16x8 bfr = *(const bf16x8*)&wsw_r[(size_t)((ntg * 4 + ks) * 64 + lane) * 8];
      bf16x8 bfl = *(const bf16x8*)&wsw_l[(size_t)((ntg * 4 + ks) * 64 + lane) * 8];
#pragma unroll
      for (int mt = 0; mt < 4; ++mt) {
        accr[mt][nt] = __builtin_amdgcn_mfma_f32_16x16x32_bf16(a[mt], bfr, accr[mt][nt], 0, 0, 0);
        accl[mt][nt] = __builtin_amdgcn_mfma_f32_16x16x32_bf16(a[mt], bfl, accl[mt][nt], 0, 0, 0);
      }
    }
  }

  // ---- right epilogue: u[e, p=wave] = sum_c (right+br)*t, butterfly over 32 cols
  {
    float bias0 = br[(wave * 2 + 0) * 16 + l16];
    float bias1 = br[(wave * 2 + 1) * 16 + l16];
#pragma unroll
    for (int mt = 0; mt < 4; ++mt)
#pragma unroll
      for (int r = 0; r < 4; ++r) {
        int row = mt * 16 + quad * 4 + r;
        float t0 = bf2f(t_s[row * 40 + l16]);
        float t1 = bf2f(t_s[row * 40 + 16 + l16]);
        float w = (accr[mt][0][r] + bias0) * t0 + (accr[mt][1][r] + bias1) * t1;
        w += __shfl_xor(w, 1, 16);
        w += __shfl_xor(w, 2, 16);
        w += __shfl_xor(w, 4, 16);
        w += __shfl_xor(w, 8, 16);
        if (l16 == 0) u_s[row * 9 + wave] = w;
      }
  }
  __syncthreads();   // u_s ready; sA reads done -> kv_s overlay safe

  // ---- left epilogue: t2 via width-8 butterfly; kv -> kv_s (overlay on sA)
  {
    u16* kv_s = sA;  // 64*72 u16 overlay (sA dead)
    float bias0 = bl[(wave * 2 + 0) * 16 + l16];
    float bias1 = bl[(wave * 2 + 1) * 16 + l16];
#pragma unroll
    for (int nt = 0; nt < 2; ++nt) {
      int m = wave * 2 + nt;
      float bias = nt ? bias1 : bias0;
#pragma unroll
      for (int mt = 0; mt < 4; ++mt)
#pragma unroll
        for (int r = 0; r < 4; ++r) {
          int row = mt * 16 + quad * 4 + r;
          float uval = u_s[row * 9 + (l16 & 7)];
          float w = (accl[mt][nt][r] + bias) * uval;
          w += __shfl_xor(w, 1, 16);
          w += __shfl_xor(w, 2, 16);
          w += __shfl_xor(w, 4, 16);
          float other = __shfl_xor(w, 8, 16);   // lanes<8 get t2l1, lanes>=8 get t2l0
          if (l16 < 4) {
            int d = l16;
            float val = w * b2_s[row * 8 + d] + other * b2_s[row * 8 + 4 + d];
            kv_s[row * 72 + m * 4 + d] = f2bf(val);
          }
        }
    }
  }
  __syncthreads();

  // ---- coalesced kv writeout: 64 rows x 64 u16 ----
  {
    const u16* kv_s = sA;
    int row = tid >> 3, c8 = (tid & 7) * 8;
    *(u16x8*)&kv[(e0 + row) * 64 + c8] = *(const u16x8*)&kv_s[row * 72 + c8];
  }
}

// ---------------- fused attention gather (score + softmax + reduce) ---------
__global__ void __launch_bounds__(256) attn_gather_kernel(
    const float* __restrict__ q, const u16* __restrict__ kvk,
    const u16* __restrict__ kvv, const int* __restrict__ rowptr,
    const int* __restrict__ eidx, float* __restrict__ outp) {
  int tid = threadIdx.x;
  int node = blockIdx.x * 4 + (tid >> 6);        // grid 2500 * 4 = NNODES
  int lane = tid & 63;
  float qv = q[(size_t)node * 64 + lane];
  int beg = rowptr[node], end = rowptr[node + 1];
  float num = 0.f, den = 0.f;
  for (int idx = beg; idx < end; ++idx) {
    int e = eidx[idx];
    float kf = bf2f(kvk[(size_t)e * 64 + lane]);
    float p = qv * kf;                            // head-dot via width-16 butterfly
    p += __shfl_xor(p, 1, 16);
    p += __shfl_xor(p, 2, 16);
    p += __shfl_xor(p, 4, 16);
    p += __shfl_xor(p, 8, 16);
    float exv = expf(p * 0.25f);                  // scale = sqrt(HM*DIM) = 4
    den += exv;
    num += exv * bf2f(kvv[(size_t)e * 64 + lane]);
  }
  outp[(size_t)node * 64 + lane] = num / fmaxf(den, 1e-9f);
}

extern "C" void kernel_launch(void* const* d_in, const int* in_sizes, int n_in,
                              void* d_out, int out_size, void* d_ws, size_t ws_size,
                              hipStream_t stream) {
  const float* b1  = (const float*)d_in[0];
  const float* b2  = (const float*)d_in[1];
  const float* ef  = (const float*)d_in[2];
  const float* f   = (const float*)d_in[3];
  const int*   src = (const int*)d_in[4];
  const int*   dst = (const int*)d_in[5];
  const float* qw  = (const float*)d_in[6];
  const float* qb  = (const float*)d_in[7];
  const float* kw1 = (const float*)d_in[8];
  const float* kb1 = (const float*)d_in[9];
  const float* kwl = (const float*)d_in[10];
  const float* kbl = (const float*)d_in[11];
  const float* kwr = (const float*)d_in[12];
  const float* kbr = (const float*)d_in[13];
  const float* vw1 = (const float*)d_in[14];
  const float* vb1 = (const float*)d_in[15];
  const float* vwl = (const float*)d_in[16];
  const float* vbl = (const float*)d_in[17];
  const float* vwr = (const float*)d_in[18];
  const float* vbr = (const float*)d_in[19];
  float* outp = (float*)d_out;

  // workspace layout
  char* ws = (char*)d_ws;
  size_t off = 0;
  auto alloc = [&](size_t bytes) {
    char* p = ws + off;
    off += (bytes + 511) & ~(size_t)511;
    return p;
  };
  u16*   Wsw  = (u16*)  alloc((size_t)4 * 32768 * 2);
  u16*   W1sw = (u16*)  alloc((size_t)2 * 4096 * 2);
  u16*   tbuf = (u16*)  alloc((size_t)NEDGE * 32 * 2);
  u16*   kvk  = (u16*)  alloc((size_t)NEDGE * 64 * 2);
  u16*   kvv  = (u16*)  alloc((size_t)NEDGE * 64 * 2);
  float* qbuf = (float*)alloc((size_t)NNODES * 64 * 4);
  int*   cnt    = (int*)alloc((size_t)NNODES * 4);
  int*   rowptr = (int*)alloc((size_t)(NNODES + 1) * 4);
  int*   cursor = (int*)alloc((size_t)NNODES * 4);
  int*   eidx   = (int*)alloc((size_t)NEDGE * 4);

  // CSR build (independent of conv pipeline)
  csr_zero_kernel<<<40, 256, 0, stream>>>(cnt);
  csr_count_kernel<<<625, 256, 0, stream>>>(dst, cnt);
  csr_scan_kernel<<<1, 256, 0, stream>>>(cnt, rowptr, cursor);
  csr_fill_kernel<<<625, 256, 0, stream>>>(dst, cursor, eidx);

  prep_w_kernel<<<512, 256, 0, stream>>>(kwr, kwl, vwr, vwl, Wsw);
  prep_w1_kernel<<<32, 256, 0, stream>>>(kw1, vw1, W1sw);
  q_kernel<<<625, 256, 0, stream>>>(f, qw, qb, qbuf);
  t_kernel<<<625, 256, 0, stream>>>(f, b1, src, tbuf);

  // conv K (one fused kernel)
  conv_fused_kernel<<<2500, 512, 0, stream>>>(ef, W1sw + 0 * 4096, kb1,
                                              Wsw + 0 * 32768, kbr,
                                              Wsw + 1 * 32768, kbl,
                                              tbuf, b2, kvk);
  // conv V
  conv_fused_kernel<<<2500, 512, 0, stream>>>(ef, W1sw + 1 * 4096, vb1,
                                              Wsw + 2 * 32768, vbr,
                                              Wsw + 3 * 32768, vbl,
                                              tbuf, b2, kvv);

  // fused attention
  attn_gather_kernel<<<2500, 256, 0, stream>>>(qbuf, kvk, kvv, rowptr, eidx, outp);
}

// Round 5
// 288.821 us; speedup vs baseline: 14.2440x; 1.3181x over previous
//
#include <hip/hip_runtime.h>
#include <hip/hip_bf16.h>
#include <math.h>

// Problem constants
#define NNODES 10000
#define NEDGE  160000
// MULT=16, NL=2, DIM=4, EDGE_DIM=32, HID=128, RANK=8, H=4, HM=4

typedef unsigned short u16;
using bf16x8 = __attribute__((ext_vector_type(8))) short;
using u16x8  = __attribute__((ext_vector_type(8))) unsigned short;
using f32x4  = __attribute__((ext_vector_type(4))) float;

static __device__ __forceinline__ u16 f2bf(float x) {
  unsigned u = __float_as_uint(x);
  u += 0x7FFFu + ((u >> 16) & 1u);     // RNE
  return (u16)(u >> 16);
}
static __device__ __forceinline__ float bf2f(u16 h) {
  return __uint_as_float(((unsigned)h) << 16);
}

// ---------------- weight swizzle: (128,256) fp32 -> frag-major bf16 ---------
// Wsw element at ((tg*4+ks)*64 + lane)*8 + j  ==  W[k][col],
//   k = ks*32 + (lane>>4)*8 + j, col = tg*16 + (lane&15).
// Fragment layouts of A and B are symmetric (16-index = lane&15,
// k = quad*8+j), so this buffer serves as A-operand of W^T @ H^T.
__global__ void prep_w_kernel(const float* __restrict__ kwr, const float* __restrict__ kwl,
                              const float* __restrict__ vwr, const float* __restrict__ vwl,
                              u16* __restrict__ Wsw) {
  int idx = blockIdx.x * 256 + threadIdx.x;      // 0..131071  (4 slots x 32768)
  int slot = idx >> 15;
  int w = idx & 32767;
  int j = w & 7, lane = (w >> 3) & 63, ks = (w >> 9) & 3, tg = w >> 11;
  int k   = ks * 32 + ((lane >> 4) << 3) + j;
  int col = (tg << 4) + (lane & 15);
  const float* s = (slot == 0) ? kwr : (slot == 1) ? kwl : (slot == 2) ? vwr : vwl;
  Wsw[idx] = f2bf(s[k * 256 + col]);
}

// ---------------- w1 swizzle: (32,128) fp32 -> B-frag-major bf16 ------------
__global__ void prep_w1_kernel(const float* __restrict__ kw1, const float* __restrict__ vw1,
                               u16* __restrict__ W1sw) {
  int idx = blockIdx.x * 256 + threadIdx.x;      // 0..8191 (2 slots x 4096)
  int slot = idx >> 12;
  int w = idx & 4095;
  int j = w & 7, lane = (w >> 3) & 63, nt = w >> 9;
  int k   = ((lane >> 4) << 3) + j;
  int col = (nt << 4) + (lane & 15);
  const float* s = (slot == 0) ? kw1 : vw1;
  W1sw[idx] = f2bf(s[k * 128 + col]);
}

// ---------------- CSR build: edges grouped by dst ---------------------------
__global__ void csr_zero_kernel(int* __restrict__ cnt) {
  int i = blockIdx.x * 256 + threadIdx.x;
  if (i < NNODES) cnt[i] = 0;
}
__global__ void csr_count_kernel(const int* __restrict__ dst, int* __restrict__ cnt) {
  int e = blockIdx.x * 256 + threadIdx.x;        // grid exact
  atomicAdd(&cnt[dst[e]], 1);
}
__global__ void __launch_bounds__(256) csr_scan_kernel(
    const int* __restrict__ cnt, int* __restrict__ rowptr, int* __restrict__ cursor) {
  __shared__ int part[256];
  int t = threadIdx.x;
  int base = t * 40;                              // 256*40 = 10240 >= NNODES
  int s = 0;
#pragma unroll 8
  for (int i = 0; i < 40; ++i) { int idx = base + i; if (idx < NNODES) s += cnt[idx]; }
  part[t] = s;
  __syncthreads();
  for (int o = 1; o < 256; o <<= 1) {
    int v = (t >= o) ? part[t - o] : 0;
    __syncthreads();
    part[t] += v;
    __syncthreads();
  }
  int run = (t == 0) ? 0 : part[t - 1];
#pragma unroll 8
  for (int i = 0; i < 40; ++i) {
    int idx = base + i;
    if (idx < NNODES) { rowptr[idx] = run; cursor[idx] = run; run += cnt[idx]; }
  }
  if (t == 255) rowptr[NNODES] = run;
}
__global__ void csr_fill_kernel(const int* __restrict__ dst, int* __restrict__ cursor,
                                int* __restrict__ eidx) {
  int e = blockIdx.x * 256 + threadIdx.x;        // grid exact
  int pos = atomicAdd(&cursor[dst[e]], 1);
  eidx[pos] = e;
}

// ---------------- Q: equivariant linear (fp32, tiny) ------------------------
__global__ void q_kernel(const float* __restrict__ f, const float* __restrict__ qw,
                         const float* __restrict__ qb, float* __restrict__ q) {
  int i = blockIdx.x * 256 + threadIdx.x;        // n*16 + o
  if (i >= NNODES * 16) return;
  int n = i >> 4, o = i & 15;
  const float* frow = f + (size_t)n * 64;
  float o0 = 0.f, o1 = 0.f, o2 = 0.f, o3 = 0.f;
#pragma unroll
  for (int m = 0; m < 16; ++m) {
    float w0 = qw[o * 16 + m];          // irrep block 0 (d = 0)
    float w1 = qw[(16 + o) * 16 + m];   // irrep block 1 (d = 1..3)
    o0 += w0 * frow[m * 4 + 0];
    o1 += w1 * frow[m * 4 + 1];
    o2 += w1 * frow[m * 4 + 2];
    o3 += w1 * frow[m * 4 + 3];
  }
  o0 += qb[o];
  float4 r = make_float4(o0, o1, o2, o3);
  *(float4*)(q + (size_t)i * 4) = r;
}

// ---------------- t + b2 permute (CSR edge order) ---------------------------
// virtual edge i = real edge eidx[i]; writes tbuf/b2p dense in sorted order
__global__ void t_kernel(const float* __restrict__ f, const float* __restrict__ b1,
                         const int* __restrict__ src, const int* __restrict__ eidx,
                         const float* __restrict__ b2,
                         u16* __restrict__ tbuf, float* __restrict__ b2p) {
  int i = blockIdx.x * 256 + threadIdx.x;        // grid covers exactly NEDGE
  int re = eidx[i];
  const float* frow = f + (size_t)src[re] * 64;
  const float* be = b1 + (size_t)re * 8;          // (4,2)
  float b[8];
#pragma unroll
  for (int k = 0; k < 8; ++k) b[k] = be[k];
  u16* tp = tbuf + (size_t)i * 32;
#pragma unroll
  for (int mh = 0; mh < 4; ++mh) {               // 4 groups of 4 m -> u16x8 stores
    u16x8 ov;
#pragma unroll
    for (int mi = 0; mi < 4; ++mi) {
      int m = mh * 4 + mi;
      float f0 = frow[m * 4 + 0], f1 = frow[m * 4 + 1], f2 = frow[m * 4 + 2], f3 = frow[m * 4 + 3];
#pragma unroll
      for (int l = 0; l < 2; ++l) {
        float t = f0 * b[0 * 2 + l] + f1 * b[1 * 2 + l] + f2 * b[2 * 2 + l] + f3 * b[3 * 2 + l];
        ov[mi * 2 + l] = f2bf(t);
      }
    }
    *(u16x8*)&tp[mh * 8] = ov;
  }
  // b2 permuted copy
  const float* b2e = b2 + (size_t)re * 8;
  float* bp = b2p + (size_t)i * 8;
  *(float4*)&bp[0] = *(const float4*)&b2e[0];
  *(float4*)&bp[4] = *(const float4*)&b2e[4];
}

// ---------------- fused equivariant conv (transposed GEMMs) -----------------
// Per 64-edge block (512 threads = 8 waves):
//  h-stage: H = gelu(ef@w1+b1) -> sA (bf16, [edge][k] pitch 136)
//  K-loop : right = wr^T@H^T, left = wl^T@H^T (M=weight-cols, N=edges)
//           wave w owns weight m-tiles {2w,2w+1} x all 4 edge n-tiles
//  epilogues: C cols are edges => rank contractions are in-register dots
//           + 2 (right) / 1 (left) shuffles per tile. 16 shuffles/lane total.
__global__ void __launch_bounds__(512) conv_fused_kernel(
    const float* __restrict__ ef, const u16* __restrict__ w1sw,
    const float* __restrict__ b1h,
    const u16* __restrict__ wsw_r, const float* __restrict__ br,
    const u16* __restrict__ wsw_l, const float* __restrict__ bl,
    const u16* __restrict__ tbuf, const float* __restrict__ b2p,
    const int* __restrict__ eidx, u16* __restrict__ kv) {
  __shared__ alignas(16) u16 sA[64 * 136];   // H tile
  __shared__ alignas(16) u16 t_s[64 * 40];   // t tile (bf16)
  __shared__ alignas(16) float b2_s[64 * 12];
  __shared__ alignas(16) float u_s[64 * 12]; // u[e][p]
  __shared__ alignas(16) float t2_s[64 * 36];// t2[e][r2]

  int tid = threadIdx.x;
  int wave = tid >> 6, lane = tid & 63, quad = lane >> 4, l16 = lane & 15;
  size_t i0 = (size_t)blockIdx.x * 64;

  // ---- stage t & b2 tiles ----
  if (tid < 256) {
    int row = tid >> 2, seg = tid & 3;
    *(uint4*)&t_s[row * 40 + seg * 8] = *(const uint4*)&tbuf[(i0 + row) * 32 + seg * 8];
  } else if (tid < 384) {
    int j = tid - 256, row = j >> 1, half = j & 1;
    *(float4*)&b2_s[row * 12 + half * 4] = *(const float4*)&b2p[(i0 + row) * 8 + half * 4];
  }

  // ---- h-stage: wave -> (mt_h = wave&3: 16 edges, ng = wave>>2: 64 hidden) ----
  {
    int mt_h = wave & 3, ng = wave >> 2;
    int pe = eidx[i0 + mt_h * 16 + l16];
    const float* ap = ef + (size_t)pe * 32 + quad * 8;
    float av[8];
    *(float4*)&av[0] = *(const float4*)&ap[0];
    *(float4*)&av[4] = *(const float4*)&ap[4];
    bf16x8 a;
#pragma unroll
    for (int j = 0; j < 8; ++j) a[j] = (short)f2bf(av[j]);
#pragma unroll
    for (int i = 0; i < 4; ++i) {
      int nt_h = ng * 4 + i;
      bf16x8 b = *(const bf16x8*)&w1sw[(size_t)(nt_h * 64 + lane) * 8];
      f32x4 acch = __builtin_amdgcn_mfma_f32_16x16x32_bf16(a, b, (f32x4){0.f, 0.f, 0.f, 0.f}, 0, 0, 0);
      int col = nt_h * 16 + l16;
      float bias = b1h[col];
#pragma unroll
      for (int r = 0; r < 4; ++r) {
        float x = acch[r] + bias;
        float g = 0.5f * x * (1.0f + erff(x * 0.7071067811865475f)); // exact gelu
        sA[(mt_h * 16 + quad * 4 + r) * 136 + col] = f2bf(g);
      }
    }
  }
  __syncthreads();

  // ---- K-loop: transposed GEMMs (A = weights, B = H) ----
  f32x4 accr[2][4], accl[2][4];
#pragma unroll
  for (int mtl = 0; mtl < 2; ++mtl)
#pragma unroll
    for (int nt = 0; nt < 4; ++nt) {
      accr[mtl][nt] = (f32x4){0.f, 0.f, 0.f, 0.f};
      accl[mtl][nt] = (f32x4){0.f, 0.f, 0.f, 0.f};
    }
#pragma unroll
  for (int ks = 0; ks < 4; ++ks) {
    bf16x8 bfrag[4];
#pragma unroll
    for (int nt = 0; nt < 4; ++nt)
      bfrag[nt] = *(const bf16x8*)&sA[(nt * 16 + l16) * 136 + ks * 32 + quad * 8];
#pragma unroll
    for (int mtl = 0; mtl < 2; ++mtl) {
      int mtg = wave * 2 + mtl;
      bf16x8 ar = *(const bf16x8*)&wsw_r[(size_t)((mtg * 4 + ks) * 64 + lane) * 8];
      bf16x8 al = *(const bf16x8*)&wsw_l[(size_t)((mtg * 4 + ks) * 64 + lane) * 8];
#pragma unroll
      for (int nt = 0; nt < 4; ++nt) {
        accr[mtl][nt] = __builtin_amdgcn_mfma_f32_16x16x32_bf16(ar, bfrag[nt], accr[mtl][nt], 0, 0, 0);
        accl[mtl][nt] = __builtin_amdgcn_mfma_f32_16x16x32_bf16(al, bfrag[nt], accl[mtl][nt], 0, 0, 0);
      }
    }
  }

  // bias preloads: weight-col = (2w+mtl)*16 + 4q + r
  float brv[2][4], blv[2][4];
#pragma unroll
  for (int mtl = 0; mtl < 2; ++mtl)
#pragma unroll
    for (int r = 0; r < 4; ++r) {
      int col = (wave * 2 + mtl) * 16 + quad * 4 + r;
      brv[mtl][r] = br[col];
      blv[mtl][r] = bl[col];
    }

  // ---- right epilogue: u[e, p=wave] = sum_c (right+br)*t ----
  // C row = w*32 + mtl*16 + 4q + r  => p = wave, c = mtl*16 + 4q + r
#pragma unroll
  for (int nt = 0; nt < 4; ++nt) {
    int e = nt * 16 + l16;
    ushort4 ta = *(const ushort4*)&t_s[e * 40 + 4 * quad];        // c: mtl=0
    ushort4 tb = *(const ushort4*)&t_s[e * 40 + 16 + 4 * quad];   // c: mtl=1
    float s = (accr[0][nt][0] + brv[0][0]) * bf2f(ta.x)
            + (accr[0][nt][1] + brv[0][1]) * bf2f(ta.y)
            + (accr[0][nt][2] + brv[0][2]) * bf2f(ta.z)
            + (accr[0][nt][3] + brv[0][3]) * bf2f(ta.w)
            + (accr[1][nt][0] + brv[1][0]) * bf2f(tb.x)
            + (accr[1][nt][1] + brv[1][1]) * bf2f(tb.y)
            + (accr[1][nt][2] + brv[1][2]) * bf2f(tb.z)
            + (accr[1][nt][3] + brv[1][3]) * bf2f(tb.w);
    s += __shfl_xor(s, 16);
    s += __shfl_xor(s, 32);
    if (quad == 0) u_s[e * 12 + wave] = s;
  }
  __syncthreads();

  // ---- left epilogue: t2[e, r2] = sum_p (left+bl)*u ----
  // C row = (2w+mtl)*16+4q+r => r2 = 4w + 2mtl + (q>>1), p = 4(q&1)+r
#pragma unroll
  for (int nt = 0; nt < 4; ++nt) {
    int e = nt * 16 + l16;
    float4 uv = *(const float4*)&u_s[e * 12 + 4 * (quad & 1)];
#pragma unroll
    for (int mtl = 0; mtl < 2; ++mtl) {
      float s = (accl[mtl][nt][0] + blv[mtl][0]) * uv.x
              + (accl[mtl][nt][1] + blv[mtl][1]) * uv.y
              + (accl[mtl][nt][2] + blv[mtl][2]) * uv.z
              + (accl[mtl][nt][3] + blv[mtl][3]) * uv.w;
      s += __shfl_xor(s, 16);                    // combine p halves (q^1)
      if ((quad & 1) == 0)
        t2_s[e * 36 + 4 * wave + 2 * mtl + (quad >> 1)] = s;
    }
  }
  __syncthreads();

  // ---- kv stage: thread -> (e = tid>>3, j = tid&7) => elements j*8..j*8+7 ----
  {
    int e = tid >> 3, j = tid & 7;
    float4 t2 = *(const float4*)&t2_s[e * 36 + 4 * j];   // r2 = 4j..4j+3
    float4 b2a = *(const float4*)&b2_s[e * 12 + 0];      // b2[e,0,:]
    float4 b2b = *(const float4*)&b2_s[e * 12 + 4];      // b2[e,1,:]
    u16x8 ov;
    ov[0] = f2bf(t2.x * b2a.x + t2.y * b2b.x);   // m=2j
    ov[1] = f2bf(t2.x * b2a.y + t2.y * b2b.y);
    ov[2] = f2bf(t2.x * b2a.z + t2.y * b2b.z);
    ov[3] = f2bf(t2.x * b2a.w + t2.y * b2b.w);
    ov[4] = f2bf(t2.z * b2a.x + t2.w * b2b.x);   // m=2j+1
    ov[5] = f2bf(t2.z * b2a.y + t2.w * b2b.y);
    ov[6] = f2bf(t2.z * b2a.z + t2.w * b2b.z);
    ov[7] = f2bf(t2.z * b2a.w + t2.w * b2b.w);
    *(u16x8*)&kv[(i0 + e) * 64 + j * 8] = ov;
  }
}

// ---------------- fused attention gather (CSR-ordered => streaming) ---------
__global__ void __launch_bounds__(256) attn_gather_kernel(
    const float* __restrict__ q, const u16* __restrict__ kvk,
    const u16* __restrict__ kvv, const int* __restrict__ rowptr,
    float* __restrict__ outp) {
  int tid = threadIdx.x;
  int node = blockIdx.x * 4 + (tid >> 6);        // grid 2500 * 4 = NNODES
  int lane = tid & 63;
  float qv = q[(size_t)node * 64 + lane];
  int beg = rowptr[node], end = rowptr[node + 1];
  float num = 0.f, den = 0.f;
  for (int idx = beg; idx < end; ++idx) {        // contiguous rows (CSR order)
    float kf = bf2f(kvk[(size_t)idx * 64 + lane]);
    float p = qv * kf;                            // head-dot via width-16 butterfly
    p += __shfl_xor(p, 1, 16);
    p += __shfl_xor(p, 2, 16);
    p += __shfl_xor(p, 4, 16);
    p += __shfl_xor(p, 8, 16);
    float exv = expf(p * 0.25f);                  // scale = sqrt(HM*DIM) = 4
    den += exv;
    num += exv * bf2f(kvv[(size_t)idx * 64 + lane]);
  }
  outp[(size_t)node * 64 + lane] = num / fmaxf(den, 1e-9f);
}

extern "C" void kernel_launch(void* const* d_in, const int* in_sizes, int n_in,
                              void* d_out, int out_size, void* d_ws, size_t ws_size,
                              hipStream_t stream) {
  const float* b1  = (const float*)d_in[0];
  const float* b2  = (const float*)d_in[1];
  const float* ef  = (const float*)d_in[2];
  const float* f   = (const float*)d_in[3];
  const int*   src = (const int*)d_in[4];
  const int*   dst = (const int*)d_in[5];
  const float* qw  = (const float*)d_in[6];
  const float* qb  = (const float*)d_in[7];
  const float* kw1 = (const float*)d_in[8];
  const float* kb1 = (const float*)d_in[9];
  const float* kwl = (const float*)d_in[10];
  const float* kbl = (const float*)d_in[11];
  const float* kwr = (const float*)d_in[12];
  const float* kbr = (const float*)d_in[13];
  const float* vw1 = (const float*)d_in[14];
  const float* vb1 = (const float*)d_in[15];
  const float* vwl = (const float*)d_in[16];
  const float* vbl = (const float*)d_in[17];
  const float* vwr = (const float*)d_in[18];
  const float* vbr = (const float*)d_in[19];
  float* outp = (float*)d_out;

  // workspace layout
  char* ws = (char*)d_ws;
  size_t off = 0;
  auto alloc = [&](size_t bytes) {
    char* p = ws + off;
    off += (bytes + 511) & ~(size_t)511;
    return p;
  };
  u16*   Wsw  = (u16*)  alloc((size_t)4 * 32768 * 2);
  u16*   W1sw = (u16*)  alloc((size_t)2 * 4096 * 2);
  u16*   tbuf = (u16*)  alloc((size_t)NEDGE * 32 * 2);
  float* b2p  = (float*)alloc((size_t)NEDGE * 8 * 4);
  u16*   kvk  = (u16*)  alloc((size_t)NEDGE * 64 * 2);
  u16*   kvv  = (u16*)  alloc((size_t)NEDGE * 64 * 2);
  float* qbuf = (float*)alloc((size_t)NNODES * 64 * 4);
  int*   cnt    = (int*)alloc((size_t)NNODES * 4);
  int*   rowptr = (int*)alloc((size_t)(NNODES + 1) * 4);
  int*   cursor = (int*)alloc((size_t)NNODES * 4);
  int*   eidx   = (int*)alloc((size_t)NEDGE * 4);

  // CSR build (everything downstream uses sorted edge order)
  csr_zero_kernel<<<40, 256, 0, stream>>>(cnt);
  csr_count_kernel<<<625, 256, 0, stream>>>(dst, cnt);
  csr_scan_kernel<<<1, 256, 0, stream>>>(cnt, rowptr, cursor);
  csr_fill_kernel<<<625, 256, 0, stream>>>(dst, cursor, eidx);

  prep_w_kernel<<<512, 256, 0, stream>>>(kwr, kwl, vwr, vwl, Wsw);
  prep_w1_kernel<<<32, 256, 0, stream>>>(kw1, vw1, W1sw);
  q_kernel<<<625, 256, 0, stream>>>(f, qw, qb, qbuf);
  t_kernel<<<625, 256, 0, stream>>>(f, b1, src, eidx, b2, tbuf, b2p);

  // conv K
  conv_fused_kernel<<<2500, 512, 0, stream>>>(ef, W1sw + 0 * 4096, kb1,
                                              Wsw + 0 * 32768, kbr,
                                              Wsw + 1 * 32768, kbl,
                                              tbuf, b2p, eidx, kvk);
  // conv V
  conv_fused_kernel<<<2500, 512, 0, stream>>>(ef, W1sw + 1 * 4096, vb1,
                                              Wsw + 2 * 32768, vbr,
                                              Wsw + 3 * 32768, vbl,
                                              tbuf, b2p, eidx, kvv);

  // fused attention (streaming reads, no atomics)
  attn_gather_kernel<<<2500, 256, 0, stream>>>(qbuf, kvk, kvv, rowptr, outp);
}

// Round 6
// 263.648 us; speedup vs baseline: 15.6041x; 1.0955x over previous
//
#include <hip/hip_runtime.h>
#include <hip/hip_bf16.h>
#include <math.h>

// Problem constants
#define NNODES 10000
#define NEDGE  160000
// MULT=16, NL=2, DIM=4, EDGE_DIM=32, HID=128, RANK=8, H=4, HM=4

typedef unsigned short u16;
using bf16x8 = __attribute__((ext_vector_type(8))) short;
using u16x8  = __attribute__((ext_vector_type(8))) unsigned short;
using f32x4  = __attribute__((ext_vector_type(4))) float;

static __device__ __forceinline__ u16 f2bf(float x) {
  unsigned u = __float_as_uint(x);
  u += 0x7FFFu + ((u >> 16) & 1u);     // RNE
  return (u16)(u >> 16);
}
static __device__ __forceinline__ float bf2f(u16 h) {
  return __uint_as_float(((unsigned)h) << 16);
}
// tanh-form gelu: x*sigmoid(x*(1.5957691 + 0.0713548*x^2)); |err| < 5e-4 abs.
// Limits exact: y->+inf => g=x; y->-inf => g=0 (rcp(inf)=0).
static __device__ __forceinline__ float fast_gelu(float x) {
  float y = x * __builtin_fmaf(0.07135481283f, x * x, 1.5957691216f);
  float e = __expf(y);
  return x - x * __builtin_amdgcn_rcpf(e + 1.0f);
}

// ---------------- fused setup: csr_zero | prep_w | prep_w1 | q --------------
// Wsw element at ((tg*4+ks)*64 + lane)*8 + j  ==  W[k][col],
//   k = ks*32 + (lane>>4)*8 + j, col = tg*16 + (lane&15).
// Serves as A-operand (W^T) of the transposed GEMMs; W1sw likewise for w1^T.
__global__ void __launch_bounds__(256) setup_kernel(
    const float* __restrict__ kwr, const float* __restrict__ kwl,
    const float* __restrict__ vwr, const float* __restrict__ vwl,
    u16* __restrict__ Wsw,
    const float* __restrict__ kw1, const float* __restrict__ vw1,
    u16* __restrict__ W1sw,
    const float* __restrict__ f, const float* __restrict__ qw,
    const float* __restrict__ qb, float* __restrict__ q,
    int* __restrict__ cnt) {
  int b = blockIdx.x, tid = threadIdx.x;
  if (b < 40) {                       // csr_zero
    int i = b * 256 + tid;
    if (i < NNODES) cnt[i] = 0;
  } else if (b < 552) {               // prep_w: 512 blocks
    int idx = (b - 40) * 256 + tid;   // 0..131071  (4 slots x 32768)
    int slot = idx >> 15;
    int w = idx & 32767;
    int j = w & 7, lane = (w >> 3) & 63, ks = (w >> 9) & 3, tg = w >> 11;
    int k   = ks * 32 + ((lane >> 4) << 3) + j;
    int col = (tg << 4) + (lane & 15);
    const float* s = (slot == 0) ? kwr : (slot == 1) ? kwl : (slot == 2) ? vwr : vwl;
    Wsw[idx] = f2bf(s[k * 256 + col]);
  } else if (b < 584) {               // prep_w1: 32 blocks
    int idx = (b - 552) * 256 + tid;  // 0..8191 (2 slots x 4096)
    int slot = idx >> 12;
    int w = idx & 4095;
    int j = w & 7, lane = (w >> 3) & 63, nt = w >> 9;
    int k   = ((lane >> 4) << 3) + j;
    int col = (nt << 4) + (lane & 15);
    const float* s = (slot == 0) ? kw1 : vw1;
    W1sw[idx] = f2bf(s[k * 128 + col]);
  } else {                            // q: 625 blocks
    int i = (b - 584) * 256 + tid;    // n*16 + o
    if (i >= NNODES * 16) return;
    int n = i >> 4, o = i & 15;
    const float* frow = f + (size_t)n * 64;
    float o0 = 0.f, o1 = 0.f, o2 = 0.f, o3 = 0.f;
#pragma unroll
    for (int m = 0; m < 16; ++m) {
      float w0 = qw[o * 16 + m];
      float w1 = qw[(16 + o) * 16 + m];
      o0 += w0 * frow[m * 4 + 0];
      o1 += w1 * frow[m * 4 + 1];
      o2 += w1 * frow[m * 4 + 2];
      o3 += w1 * frow[m * 4 + 3];
    }
    o0 += qb[o];
    float4 r = make_float4(o0, o1, o2, o3);
    *(float4*)(q + (size_t)i * 4) = r;
  }
}

// ---------------- CSR build: edges grouped by dst ---------------------------
__global__ void csr_count_kernel(const int* __restrict__ dst, int* __restrict__ cnt) {
  int e = blockIdx.x * 256 + threadIdx.x;        // grid exact
  atomicAdd(&cnt[dst[e]], 1);
}
__global__ void __launch_bounds__(1024) csr_scan_kernel(
    const int* __restrict__ cnt, int* __restrict__ rowptr, int* __restrict__ cursor) {
  __shared__ int part[1024];
  int t = threadIdx.x;
  int base = t * 10;                              // 1024*10 = 10240 >= NNODES
  int s = 0;
#pragma unroll
  for (int i = 0; i < 10; ++i) { int idx = base + i; if (idx < NNODES) s += cnt[idx]; }
  part[t] = s;
  __syncthreads();
  for (int o = 1; o < 1024; o <<= 1) {
    int v = (t >= o) ? part[t - o] : 0;
    __syncthreads();
    part[t] += v;
    __syncthreads();
  }
  int run = (t == 0) ? 0 : part[t - 1];
#pragma unroll
  for (int i = 0; i < 10; ++i) {
    int idx = base + i;
    if (idx < NNODES) { rowptr[idx] = run; cursor[idx] = run; run += cnt[idx]; }
  }
  if (t == 1023) rowptr[NNODES] = run;
}
__global__ void csr_fill_kernel(const int* __restrict__ dst, int* __restrict__ cursor,
                                int* __restrict__ eidx) {
  int e = blockIdx.x * 256 + threadIdx.x;        // grid exact
  int pos = atomicAdd(&cursor[dst[e]], 1);
  eidx[pos] = e;
}

// ---------------- t + b2 permute (CSR edge order) ---------------------------
__global__ void t_kernel(const float* __restrict__ f, const float* __restrict__ b1,
                         const int* __restrict__ src, const int* __restrict__ eidx,
                         const float* __restrict__ b2,
                         u16* __restrict__ tbuf, float* __restrict__ b2p) {
  int i = blockIdx.x * 256 + threadIdx.x;        // grid covers exactly NEDGE
  int re = eidx[i];
  const float* frow = f + (size_t)src[re] * 64;
  const float* be = b1 + (size_t)re * 8;          // (4,2)
  float b[8];
#pragma unroll
  for (int k = 0; k < 8; ++k) b[k] = be[k];
  u16* tp = tbuf + (size_t)i * 32;
#pragma unroll
  for (int mh = 0; mh < 4; ++mh) {
    u16x8 ov;
#pragma unroll
    for (int mi = 0; mi < 4; ++mi) {
      int m = mh * 4 + mi;
      float f0 = frow[m * 4 + 0], f1 = frow[m * 4 + 1], f2 = frow[m * 4 + 2], f3 = frow[m * 4 + 3];
#pragma unroll
      for (int l = 0; l < 2; ++l) {
        float t = f0 * b[0 * 2 + l] + f1 * b[1 * 2 + l] + f2 * b[2 * 2 + l] + f3 * b[3 * 2 + l];
        ov[mi * 2 + l] = f2bf(t);
      }
    }
    *(u16x8*)&tp[mh * 8] = ov;
  }
  const float* b2e = b2 + (size_t)re * 8;
  float* bp = b2p + (size_t)i * 8;
  *(float4*)&bp[0] = *(const float4*)&b2e[0];
  *(float4*)&bp[4] = *(const float4*)&b2e[4];
}

// ---------------- fused equivariant conv (transposed GEMMs) -----------------
// Per 64-edge block (512 threads = 8 waves):
//  stage  : ef tile (bf16) -> efs; t tile -> t_s; b2 tile -> b2_s
//  h-stage: H^T = w1^T @ ef^T via MFMA (A=W1sw, B=efs frags); gelu; packed
//           ds_write_b64 into sA[edge][hid] (pitch 136)
//  K-loop : right = wr^T@H^T, left = wl^T@H^T (M=weight-cols, N=edges)
//  epilogues: in-register rank contractions + 2/1 shuffles per tile
__global__ void __launch_bounds__(512) conv_fused_kernel(
    const float* __restrict__ ef, const u16* __restrict__ w1sw,
    const float* __restrict__ b1h,
    const u16* __restrict__ wsw_r, const float* __restrict__ br,
    const u16* __restrict__ wsw_l, const float* __restrict__ bl,
    const u16* __restrict__ tbuf, const float* __restrict__ b2p,
    const int* __restrict__ eidx, u16* __restrict__ kv) {
  __shared__ alignas(16) u16 sA[64 * 136];    // H tile [edge][hid]
  __shared__ alignas(16) u16 t_s[64 * 40];    // t tile (bf16)
  __shared__ alignas(16) float b2_s[64 * 12];
  __shared__ alignas(16) float u_s[64 * 12];  // u[e][p]
  __shared__ alignas(16) float t2_pool[64 * 36]; // t2[e][r2]; overlays efs
  float* t2_s = t2_pool;
  u16*   efs  = (u16*)t2_pool;                // ef tile bf16 [edge][k] pitch 40

  int tid = threadIdx.x;
  int wave = tid >> 6, lane = tid & 63, quad = lane >> 4, l16 = lane & 15;
  size_t i0 = (size_t)blockIdx.x * 64;

  // ---- stage tiles ----
  if (tid < 256) {            // ef tile: 64 rows x 32 f32 -> bf16
    int row = tid >> 2, seg = tid & 3;
    int pe = eidx[i0 + row];
    const float* ap = ef + (size_t)pe * 32 + seg * 8;
    float4 v0 = *(const float4*)&ap[0];
    float4 v1 = *(const float4*)&ap[4];
    u16x8 ov;
    ov[0] = f2bf(v0.x); ov[1] = f2bf(v0.y); ov[2] = f2bf(v0.z); ov[3] = f2bf(v0.w);
    ov[4] = f2bf(v1.x); ov[5] = f2bf(v1.y); ov[6] = f2bf(v1.z); ov[7] = f2bf(v1.w);
    *(u16x8*)&efs[row * 40 + seg * 8] = ov;
    if (tid < 128) {          // b2 tile: 64 rows x 8 f32
      int r2 = tid >> 1, half = tid & 1;
      *(float4*)&b2_s[r2 * 12 + half * 4] = *(const float4*)&b2p[(i0 + r2) * 8 + half * 4];
    }
  } else {                    // t tile: 64 rows x 32 u16
    int j = tid - 256;
    int row = j >> 2, seg = j & 3;
    *(uint4*)&t_s[row * 40 + seg * 8] = *(const uint4*)&tbuf[(i0 + row) * 32 + seg * 8];
  }
  __syncthreads();

  // ---- h-stage: wave owns hid-tile `wave` (16 cols), iterates 4 edge tiles ----
  {
    bf16x8 aw = *(const bf16x8*)&w1sw[(size_t)(wave * 64 + lane) * 8];  // A = w1^T
    float4 bias_h = *(const float4*)&b1h[wave * 16 + quad * 4];
#pragma unroll
    for (int nt = 0; nt < 4; ++nt) {
      bf16x8 be = *(const bf16x8*)&efs[(nt * 16 + l16) * 40 + quad * 8]; // B = ef^T
      f32x4 acch = __builtin_amdgcn_mfma_f32_16x16x32_bf16(aw, be, (f32x4){0.f, 0.f, 0.f, 0.f}, 0, 0, 0);
      ushort4 hv;
      hv.x = f2bf(fast_gelu(acch[0] + bias_h.x));
      hv.y = f2bf(fast_gelu(acch[1] + bias_h.y));
      hv.z = f2bf(fast_gelu(acch[2] + bias_h.z));
      hv.w = f2bf(fast_gelu(acch[3] + bias_h.w));
      *(ushort4*)&sA[(nt * 16 + l16) * 136 + wave * 16 + quad * 4] = hv;
    }
  }
  __syncthreads();

  // ---- K-loop: transposed GEMMs (A = weights, B = H) ----
  f32x4 accr[2][4], accl[2][4];
#pragma unroll
  for (int mtl = 0; mtl < 2; ++mtl)
#pragma unroll
    for (int nt = 0; nt < 4; ++nt) {
      accr[mtl][nt] = (f32x4){0.f, 0.f, 0.f, 0.f};
      accl[mtl][nt] = (f32x4){0.f, 0.f, 0.f, 0.f};
    }
#pragma unroll
  for (int ks = 0; ks < 4; ++ks) {
    bf16x8 bfrag[4];
#pragma unroll
    for (int nt = 0; nt < 4; ++nt)
      bfrag[nt] = *(const bf16x8*)&sA[(nt * 16 + l16) * 136 + ks * 32 + quad * 8];
#pragma unroll
    for (int mtl = 0; mtl < 2; ++mtl) {
      int mtg = wave * 2 + mtl;
      bf16x8 ar = *(const bf16x8*)&wsw_r[(size_t)((mtg * 4 + ks) * 64 + lane) * 8];
      bf16x8 al = *(const bf16x8*)&wsw_l[(size_t)((mtg * 4 + ks) * 64 + lane) * 8];
#pragma unroll
      for (int nt = 0; nt < 4; ++nt) {
        accr[mtl][nt] = __builtin_amdgcn_mfma_f32_16x16x32_bf16(ar, bfrag[nt], accr[mtl][nt], 0, 0, 0);
        accl[mtl][nt] = __builtin_amdgcn_mfma_f32_16x16x32_bf16(al, bfrag[nt], accl[mtl][nt], 0, 0, 0);
      }
    }
  }

  // bias preloads: weight-col = (2w+mtl)*16 + 4q + r
  float brv[2][4], blv[2][4];
#pragma unroll
  for (int mtl = 0; mtl < 2; ++mtl)
#pragma unroll
    for (int r = 0; r < 4; ++r) {
      int col = (wave * 2 + mtl) * 16 + quad * 4 + r;
      brv[mtl][r] = br[col];
      blv[mtl][r] = bl[col];
    }

  // ---- right epilogue: u[e, p=wave] = sum_c (right+br)*t ----
#pragma unroll
  for (int nt = 0; nt < 4; ++nt) {
    int e = nt * 16 + l16;
    ushort4 ta = *(const ushort4*)&t_s[e * 40 + 4 * quad];        // c: mtl=0
    ushort4 tb = *(const ushort4*)&t_s[e * 40 + 16 + 4 * quad];   // c: mtl=1
    float s = (accr[0][nt][0] + brv[0][0]) * bf2f(ta.x)
            + (accr[0][nt][1] + brv[0][1]) * bf2f(ta.y)
            + (accr[0][nt][2] + brv[0][2]) * bf2f(ta.z)
            + (accr[0][nt][3] + brv[0][3]) * bf2f(ta.w)
            + (accr[1][nt][0] + brv[1][0]) * bf2f(tb.x)
            + (accr[1][nt][1] + brv[1][1]) * bf2f(tb.y)
            + (accr[1][nt][2] + brv[1][2]) * bf2f(tb.z)
            + (accr[1][nt][3] + brv[1][3]) * bf2f(tb.w);
    s += __shfl_xor(s, 16);
    s += __shfl_xor(s, 32);
    if (quad == 0) u_s[e * 12 + wave] = s;
  }
  __syncthreads();   // u_s ready; efs reads long done -> t2_s overlay safe

  // ---- left epilogue: t2[e, r2] = sum_p (left+bl)*u ----
#pragma unroll
  for (int nt = 0; nt < 4; ++nt) {
    int e = nt * 16 + l16;
    float4 uv = *(const float4*)&u_s[e * 12 + 4 * (quad & 1)];
#pragma unroll
    for (int mtl = 0; mtl < 2; ++mtl) {
      float s = (accl[mtl][nt][0] + blv[mtl][0]) * uv.x
              + (accl[mtl][nt][1] + blv[mtl][1]) * uv.y
              + (accl[mtl][nt][2] + blv[mtl][2]) * uv.z
              + (accl[mtl][nt][3] + blv[mtl][3]) * uv.w;
      s += __shfl_xor(s, 16);                    // combine p halves (q^1)
      if ((quad & 1) == 0)
        t2_s[e * 36 + 4 * wave + 2 * mtl + (quad >> 1)] = s;
    }
  }
  __syncthreads();

  // ---- kv stage: thread -> (e = tid>>3, j = tid&7) => elements j*8..j*8+7 ----
  {
    int e = tid >> 3, j = tid & 7;
    float4 t2 = *(const float4*)&t2_s[e * 36 + 4 * j];   // r2 = 4j..4j+3
    float4 b2a = *(const float4*)&b2_s[e * 12 + 0];
    float4 b2b = *(const float4*)&b2_s[e * 12 + 4];
    u16x8 ov;
    ov[0] = f2bf(t2.x * b2a.x + t2.y * b2b.x);   // m=2j
    ov[1] = f2bf(t2.x * b2a.y + t2.y * b2b.y);
    ov[2] = f2bf(t2.x * b2a.z + t2.y * b2b.z);
    ov[3] = f2bf(t2.x * b2a.w + t2.y * b2b.w);
    ov[4] = f2bf(t2.z * b2a.x + t2.w * b2b.x);   // m=2j+1
    ov[5] = f2bf(t2.z * b2a.y + t2.w * b2b.y);
    ov[6] = f2bf(t2.z * b2a.z + t2.w * b2b.z);
    ov[7] = f2bf(t2.z * b2a.w + t2.w * b2b.w);
    *(u16x8*)&kv[(i0 + e) * 64 + j * 8] = ov;
  }
}

// ---------------- fused attention gather (CSR-ordered => streaming) ---------
__global__ void __launch_bounds__(256) attn_gather_kernel(
    const float* __restrict__ q, const u16* __restrict__ kvk,
    const u16* __restrict__ kvv, const int* __restrict__ rowptr,
    float* __restrict__ outp) {
  int tid = threadIdx.x;
  int node = blockIdx.x * 4 + (tid >> 6);        // grid 2500 * 4 = NNODES
  int lane = tid & 63;
  float qv = q[(size_t)node * 64 + lane];
  int beg = rowptr[node], end = rowptr[node + 1];
  float num = 0.f, den = 0.f;
  for (int idx = beg; idx < end; ++idx) {        // contiguous rows (CSR order)
    float kf = bf2f(kvk[(size_t)idx * 64 + lane]);
    float p = qv * kf;                            // head-dot via width-16 butterfly
    p += __shfl_xor(p, 1, 16);
    p += __shfl_xor(p, 2, 16);
    p += __shfl_xor(p, 4, 16);
    p += __shfl_xor(p, 8, 16);
    float exv = __expf(p * 0.25f);                // scale = sqrt(HM*DIM) = 4
    den += exv;
    num += exv * bf2f(kvv[(size_t)idx * 64 + lane]);
  }
  outp[(size_t)node * 64 + lane] = num / fmaxf(den, 1e-9f);
}

extern "C" void kernel_launch(void* const* d_in, const int* in_sizes, int n_in,
                              void* d_out, int out_size, void* d_ws, size_t ws_size,
                              hipStream_t stream) {
  const float* b1  = (const float*)d_in[0];
  const float* b2  = (const float*)d_in[1];
  const float* ef  = (const float*)d_in[2];
  const float* f   = (const float*)d_in[3];
  const int*   src = (const int*)d_in[4];
  const int*   dst = (const int*)d_in[5];
  const float* qw  = (const float*)d_in[6];
  const float* qb  = (const float*)d_in[7];
  const float* kw1 = (const float*)d_in[8];
  const float* kb1 = (const float*)d_in[9];
  const float* kwl = (const float*)d_in[10];
  const float* kbl = (const float*)d_in[11];
  const float* kwr = (const float*)d_in[12];
  const float* kbr = (const float*)d_in[13];
  const float* vw1 = (const float*)d_in[14];
  const float* vb1 = (const float*)d_in[15];
  const float* vwl = (const float*)d_in[16];
  const float* vbl = (const float*)d_in[17];
  const float* vwr = (const float*)d_in[18];
  const float* vbr = (const float*)d_in[19];
  float* outp = (float*)d_out;

  // workspace layout
  char* ws = (char*)d_ws;
  size_t off = 0;
  auto alloc = [&](size_t bytes) {
    char* p = ws + off;
    off += (bytes + 511) & ~(size_t)511;
    return p;
  };
  u16*   Wsw  = (u16*)  alloc((size_t)4 * 32768 * 2);
  u16*   W1sw = (u16*)  alloc((size_t)2 * 4096 * 2);
  u16*   tbuf = (u16*)  alloc((size_t)NEDGE * 32 * 2);
  float* b2p  = (float*)alloc((size_t)NEDGE * 8 * 4);
  u16*   kvk  = (u16*)  alloc((size_t)NEDGE * 64 * 2);
  u16*   kvv  = (u16*)  alloc((size_t)NEDGE * 64 * 2);
  float* qbuf = (float*)alloc((size_t)NNODES * 64 * 4);
  int*   cnt    = (int*)alloc((size_t)NNODES * 4);
  int*   rowptr = (int*)alloc((size_t)(NNODES + 1) * 4);
  int*   cursor = (int*)alloc((size_t)NNODES * 4);
  int*   eidx   = (int*)alloc((size_t)NEDGE * 4);

  // setup: csr_zero | prep_w | prep_w1 | q  (all independent)
  setup_kernel<<<1209, 256, 0, stream>>>(kwr, kwl, vwr, vwl, Wsw,
                                         kw1, vw1, W1sw,
                                         f, qw, qb, qbuf, cnt);
  // CSR build
  csr_count_kernel<<<625, 256, 0, stream>>>(dst, cnt);
  csr_scan_kernel<<<1, 1024, 0, stream>>>(cnt, rowptr, cursor);
  csr_fill_kernel<<<625, 256, 0, stream>>>(dst, cursor, eidx);

  t_kernel<<<625, 256, 0, stream>>>(f, b1, src, eidx, b2, tbuf, b2p);

  // conv K
  conv_fused_kernel<<<2500, 512, 0, stream>>>(ef, W1sw + 0 * 4096, kb1,
                                              Wsw + 0 * 32768, kbr,
                                              Wsw + 1 * 32768, kbl,
                                              tbuf, b2p, eidx, kvk);
  // conv V
  conv_fused_kernel<<<2500, 512, 0, stream>>>(ef, W1sw + 1 * 4096, vb1,
                                              Wsw + 2 * 32768, vbr,
                                              Wsw + 3 * 32768, vbl,
                                              tbuf, b2p, eidx, kvv);

  // fused attention (streaming reads, no atomics)
  attn_gather_kernel<<<2500, 256, 0, stream>>>(qbuf, kvk, kvv, rowptr, outp);
}